// Round 18
// baseline (139.318 us; speedup 1.0000x reference)
//
#include <hip/hip_runtime.h>
#include <hip/hip_bf16.h>

// Sizes (fixed): b=2, n=1024, dim=512, h=8, L=8, dh=64
// exp(-d2/T) with T=0.1 -> exp2(C*d2), C = -10*log2(e)
#define CEXP (-14.4269504088896340736f)

typedef __attribute__((ext_vector_type(8))) short bfrag8;   // 8 bf16 (4 VGPR) MFMA operand
typedef __attribute__((ext_vector_type(4))) float fvec4;    // MFMA accumulator / 16B vec
typedef __attribute__((ext_vector_type(8))) unsigned short ushort8;
typedef __attribute__((ext_vector_type(4))) unsigned short ushort4v;

__device__ inline unsigned short f2bf(float f) {            // RNE float->bf16
    unsigned u = __builtin_bit_cast(unsigned, f);
    u += 0x7fffu + ((u >> 16) & 1u);
    return (unsigned short)(u >> 16);
}
__device__ inline float bf2f(unsigned short h) {
    unsigned u = ((unsigned)h) << 16;
    return __builtin_bit_cast(float, u);
}

// Wave64 sum via DPP (rocPRIM pattern). ctrl/rmask immediates via template params.
template <int CTRL, int RMASK>
__device__ __forceinline__ float dpp_add(float v) {
    int m = __builtin_amdgcn_update_dpp(0, __builtin_bit_cast(int, v), CTRL, RMASK, 0xf, true);
    return v + __builtin_bit_cast(float, m);
}
__device__ __forceinline__ float wave_sum64(float v) {
    v = dpp_add<0xB1,  0xf>(v);   // quad_perm(1,0,3,2)
    v = dpp_add<0x4E,  0xf>(v);   // quad_perm(2,3,0,1)
    v = dpp_add<0x141, 0xf>(v);   // row_half_mirror
    v = dpp_add<0x140, 0xf>(v);   // row_mirror
    v = dpp_add<0x142, 0xa>(v);   // row_bcast15 into rows 1,3
    v = dpp_add<0x143, 0xc>(v);   // row_bcast31 into rows 2,3
    return __builtin_bit_cast(float, __builtin_amdgcn_readlane(__builtin_bit_cast(int, v), 63));
}

// ---------------- K_B: Wqp/Wkp projections; extract Wv; WoutT -> bf16 hi/lo ----------
__global__ __launch_bounds__(256) void k_wproj(const float* __restrict__ Wqkv,
                                               const float* __restrict__ theta,
                                               const float* __restrict__ Wout,
                                               float* __restrict__ Wqp,
                                               float* __restrict__ Wkp,
                                               float* __restrict__ Wv,
                                               unsigned short* __restrict__ WoThi,
                                               unsigned short* __restrict__ WoTlo) {
    __shared__ float th_s[64 * 65];
    __shared__ float ts2[64 * 65];
    int tid = threadIdx.x;
    int hl = tid & 63, cl = tid >> 6;
    #pragma unroll
    for (int i = 0; i < 16; ++i) {
        int r = cl * 16 + i;
        th_s[r * 65 + hl] = theta[r * 64 + hl];
    }
    __syncthreads();
    const float* ts = th_s + hl * 65;
    float ss = 0.f;
    #pragma unroll 8
    for (int d = 0; d < 64; ++d) ss = fmaf(ts[d], ts[d], ss);
    float inv = rsqrtf(ss);
    int c = blockIdx.x * 4 + cl;
    int h = hl >> 3;
    const float* wq = Wqkv + c * 1536 + h * 64;
    const float* wk = wq + 512;
    float aq = 0.f, ak = 0.f;
    #pragma unroll 4
    for (int d = 0; d < 64; ++d) {
        float tv = ts[d];
        aq = fmaf(wq[d], tv, aq);
        ak = fmaf(wk[d], tv, ak);
    }
    Wqp[c * 64 + hl] = aq * inv;
    Wkp[c * 64 + hl] = ak * inv;

    int c0b = blockIdx.x * 4;
    const float4* src = (const float4*)(Wqkv + 1024);
    float4* dst = (float4*)Wv;
    #pragma unroll
    for (int j = 0; j < 2; ++j) {
        int idx = j * 256 + tid;
        int cr = c0b + (idx >> 7), o4 = idx & 127;
        dst[cr * 128 + o4] = src[cr * 384 + o4];
    }

    // blocks 0..63: WoutT[n][c] = Wout[c][n] as bf16 hi/lo (64x64 tiles, LDS transpose)
    if (blockIdx.x < 64) {
        int r0 = (blockIdx.x >> 3) * 64;     // Wout row (= c of WoutT)
        int c0 = (blockIdx.x & 7) * 64;      // Wout col (= n of WoutT)
        int cc = tid & 63, rr = tid >> 6;
        #pragma unroll
        for (int k = 0; k < 16; ++k) {
            int r = rr + 4 * k;
            ts2[r * 65 + cc] = Wout[(r0 + r) * 512 + c0 + cc];
        }
        __syncthreads();
        int kk = tid & 63, nn = tid >> 6;    // kk = inner (coalesced) dim of WoutT
        #pragma unroll
        for (int i = 0; i < 16; ++i) {
            int n = nn + 4 * i;
            float v = ts2[kk * 65 + n];
            unsigned short hi = f2bf(v);
            WoThi[(size_t)(c0 + n) * 512 + r0 + kk] = hi;
            WoTlo[(size_t)(c0 + n) * 512 + r0 + kk] = f2bf(v - bf2f(hi));
        }
    }
}

// ---------------- K_CD merged: qkp (blocks 0-511) + vproj (blocks 512-1023) ----------
// qkp: 4 rows; 512 thr = 128 cols x 4 K-quarters; LDS combine; fvec4 stores.
// vproj: 8 rows x 256 cols (col-half); 512 thr = 256 cols x 2 K-halves; ushort8 stores.
__global__ __launch_bounds__(512) void k_proj(const float* __restrict__ x,
                                              const float* __restrict__ Wqp,
                                              const float* __restrict__ Wkp,
                                              const float* __restrict__ Wv,
                                              float* __restrict__ qp,
                                              float* __restrict__ kp,
                                              unsigned short* __restrict__ vThi,
                                              unsigned short* __restrict__ vTlo) {
    __shared__ float xs[8 * 512];            // 16 KB staging
    __shared__ float combraw[4096];          // 16 KB combine scratch
    int tid = threadIdx.x;
    if (blockIdx.x < 512) {
        // ---------- qkp ----------
        float (*comb)[128][4] = (float(*)[128][4])combraw;
        int i0 = blockIdx.x * 4;
        const float4* xg = (const float4*)(x + i0 * 512);
        ((float4*)xs)[tid] = xg[tid];        // 4 rows
        __syncthreads();

        int t  = tid & 127;
        int kh = tid >> 7;                   // 0..3
        int hl = t & 63;
        const float* Bm = (t & 64) ? Wkp : Wqp;
        float a[4] = {0.f, 0.f, 0.f, 0.f};
        int c4b = kh * 32;
        for (int c4 = c4b; c4 < c4b + 32; ++c4) {
            float b0 = Bm[(c4 * 4 + 0) * 64 + hl];
            float b1 = Bm[(c4 * 4 + 1) * 64 + hl];
            float b2 = Bm[(c4 * 4 + 2) * 64 + hl];
            float b3 = Bm[(c4 * 4 + 3) * 64 + hl];
            #pragma unroll
            for (int r = 0; r < 4; ++r) {
                float4 xv = *(const float4*)(xs + r * 512 + c4 * 4);
                a[r] = fmaf(xv.x, b0, fmaf(xv.y, b1, fmaf(xv.z, b2, fmaf(xv.w, b3, a[r]))));
            }
        }
        #pragma unroll
        for (int r = 0; r < 4; ++r) comb[kh][t][r] = a[r];
        __syncthreads();

        if (tid < 128) {
            int hl2 = tid & 63;
            int h = hl2 >> 3, l = hl2 & 7;
            float* dstp = (tid & 64) ? kp : qp;
            int b = i0 >> 10, i = i0 & 1023;
            fvec4 st;
            #pragma unroll
            for (int r = 0; r < 4; ++r)
                st[r] = (comb[0][tid][r] + comb[1][tid][r] + comb[2][tid][r] + comb[3][tid][r]) * 0.125f;
            *(fvec4*)(dstp + ((b * 8 + h) * 8 + l) * 1024 + i) = st;
        }
    } else {
        // ---------- vproj ----------
        float (*comb)[256][8] = (float(*)[256][8])combraw;
        int blk2 = blockIdx.x - 512;         // 0..511
        int ch = blk2 & 1;
        int i0 = (blk2 >> 1) * 8;
        const float4* xg = (const float4*)(x + i0 * 512);
        #pragma unroll
        for (int j = 0; j < 2; ++j) ((float4*)xs)[j * 512 + tid] = xg[j * 512 + tid];
        __syncthreads();

        int t  = tid & 255;
        int kh = tid >> 8;                   // 0..1
        int col = ch * 256 + t;
        const float* wp = Wv + col;
        float a[8];
        #pragma unroll
        for (int r = 0; r < 8; ++r) a[r] = 0.f;
        int c4b = kh * 64;
        for (int c4 = c4b; c4 < c4b + 64; ++c4) {
            float w0 = wp[(c4 * 4 + 0) * 512];
            float w1 = wp[(c4 * 4 + 1) * 512];
            float w2 = wp[(c4 * 4 + 2) * 512];
            float w3 = wp[(c4 * 4 + 3) * 512];
            #pragma unroll
            for (int r = 0; r < 8; ++r) {
                float4 xv = *(const float4*)(xs + r * 512 + c4 * 4);
                a[r] = fmaf(xv.x, w0, fmaf(xv.y, w1, fmaf(xv.z, w2, fmaf(xv.w, w3, a[r]))));
            }
        }
        #pragma unroll
        for (int r = 0; r < 8; ++r) comb[kh][t][r] = a[r];
        __syncthreads();

        if (tid < 256) {
            int col2 = ch * 256 + tid;
            int h = col2 >> 6, d = col2 & 63;
            int b = i0 >> 10, ib = i0 & 1023;
            ushort8 vh, vl;
            #pragma unroll
            for (int r = 0; r < 8; ++r) {
                float v = comb[0][tid][r] + comb[1][tid][r];
                unsigned short hi = f2bf(v);
                vh[r] = hi;
                vl[r] = f2bf(v - bf2f(hi));
            }
            size_t off = (size_t)(b * 8 + h) * 65536 + (size_t)d * 1024 + ib;
            *(ushort8*)(vThi + off) = vh;
            *(ushort8*)(vTlo + off) = vl;
        }
    }
}

// ---------------- K_E: fused attention rows + MFMA PV; 512 thr / 8 waves --------------
// r15-exact except: attn stores are PLAIN (L2/L3-cached), not nontemporal — A/B test.
__global__ __launch_bounds__(512) void k_attn_pv(const float* __restrict__ qp,
                                                 const float* __restrict__ kp,
                                                 const unsigned short* __restrict__ vThi,
                                                 const unsigned short* __restrict__ vTlo,
                                                 float* __restrict__ attn,
                                                 float* __restrict__ oh) {
    __shared__ float s_buf[8 * 1024];        // kp (f32) phase 1; P hi/lo bf16 [16][1024] phase 2
    __shared__ float sc[4 * 64 * 4];         // 4 KB split-K combine scratch
    int bx = blockIdx.x;                     // 2048
    int idx = bx >> 3;                       // [0,256)
    int bh = (bx & 7) * 2 + (idx >> 7);      // XCD-aware: 2 bh per XCD -> L2-resident vT
    int rowbase = (idx & 127) * 8;
    int tid = threadIdx.x;
    int w = tid >> 6, lane = tid & 63;

    const float4* kp4 = (const float4*)(kp + bh * 8192);
    float4* kps4 = (float4*)s_buf;
    #pragma unroll
    for (int k = 0; k < 4; ++k) kps4[k * 512 + tid] = kp4[k * 512 + tid];

    int r = rowbase + w;
    float qv[8];
    #pragma unroll
    for (int l = 0; l < 8; ++l) qv[l] = qp[bh * 8192 + l * 1024 + r];
    __syncthreads();

    const fvec4 CE4 = {CEXP, CEXP, CEXP, CEXP};
    fvec4 acc4[4];
    #pragma unroll
    for (int mm = 0; mm < 4; ++mm) acc4[mm] = (fvec4){0.f, 0.f, 0.f, 0.f};

    for (int l = 0; l < 8; ++l) {
        fvec4 kv4[4], e4[4];
        #pragma unroll
        for (int mm = 0; mm < 4; ++mm)
            kv4[mm] = *(const fvec4*)(s_buf + l * 1024 + mm * 256 + lane * 4);
        float sqs = -2.f * CEXP * qv[l];
        fvec4 sq4 = {sqs, sqs, sqs, sqs};
        fvec4 sum4 = {0.f, 0.f, 0.f, 0.f};
        #pragma unroll
        for (int mm = 0; mm < 4; ++mm) {
            fvec4 k2 = (kv4[mm] * kv4[mm]) * CE4;
            fvec4 t  = sq4 * kv4[mm] + k2;
            fvec4 e;
            e[0] = __builtin_amdgcn_exp2f(t[0]);
            e[1] = __builtin_amdgcn_exp2f(t[1]);
            e[2] = __builtin_amdgcn_exp2f(t[2]);
            e[3] = __builtin_amdgcn_exp2f(t[3]);
            e4[mm] = e;
            sum4 += e;
        }
        float s = (sum4[0] + sum4[1]) + (sum4[2] + sum4[3]);
        float inv = 0.125f * __builtin_amdgcn_rcpf(wave_sum64(s));
        fvec4 inv4 = {inv, inv, inv, inv};
        #pragma unroll
        for (int mm = 0; mm < 4; ++mm) acc4[mm] = e4[mm] * inv4 + acc4[mm];
    }

    __syncthreads();   // all waves done reading kp from s_buf

    unsigned short* ps = (unsigned short*)s_buf;
    int swz = w << 3;
    #pragma unroll
    for (int mm = 0; mm < 4; ++mm) {
        ushort4v h4, l4;
        #pragma unroll
        for (int jj = 0; jj < 4; ++jj) {
            float v = acc4[mm][jj];
            unsigned short hi = f2bf(v);
            h4[jj] = hi;
            l4[jj] = f2bf(v - bf2f(hi));
        }
        int j0 = mm * 256 + lane * 4;
        *(ushort4v*)(ps + w * 1024 + (j0 ^ swz))       = h4;
        *(ushort4v*)(ps + (w + 8) * 1024 + (j0 ^ swz)) = l4;
    }
    __syncthreads();

    // attn stores: plain (cached) — let L2/L3 absorb the 67 MB stream.
    float* aR = attn + ((size_t)(bh * 1024 + r)) * 1024;
    #pragma unroll
    for (int mm = 0; mm < 4; ++mm)
        *(fvec4*)(aR + mm * 256 + lane * 4) = acc4[mm];

    // Phase 2: wave w -> cols n0..n0+15, K-half kh; pairs (w, w+4) combine via LDS.
    int n0 = (w & 3) * 16;
    int kh = w >> 2;
    int ar  = lane & 15;
    int asw = (ar & 7) << 3;
    int ak  = (lane >> 4) * 8;
    const unsigned short* ap = ps + ar * 1024;
    size_t boff = (size_t)bh * 65536 + (size_t)(n0 + (lane & 15)) * 1024 + ak;
    const unsigned short* bh_p = vThi + boff;
    const unsigned short* bl_p = vTlo + boff;
    fvec4 c2 = {0.f, 0.f, 0.f, 0.f};
    #pragma unroll 4
    for (int s = kh * 16; s < kh * 16 + 16; ++s) {
        bfrag8 a  = *(const bfrag8*)(ap + ((s * 32 + ak) ^ asw));
        bfrag8 vh = *(const bfrag8*)(bh_p + s * 32);
        bfrag8 vl = *(const bfrag8*)(bl_p + s * 32);
        c2 = __builtin_amdgcn_mfma_f32_16x16x32_bf16(a, vh, c2, 0, 0, 0);
        c2 = __builtin_amdgcn_mfma_f32_16x16x32_bf16(a, vl, c2, 0, 0, 0);
    }
    if (w >= 4) {
        #pragma unroll
        for (int q = 0; q < 4; ++q) sc[(w - 4) * 256 + lane * 4 + q] = c2[q];
    }
    __syncthreads();
    if (w < 4) {
        int b = bh >> 3, h = bh & 7;
        #pragma unroll
        for (int q = 0; q < 4; ++q) {
            float t = c2[q] + sc[w * 256 + lane * 4 + q];
            t += __shfl_xor(t, 32);               // hi row + lo row
            if (lane < 32) {
                int row = rowbase + (lane >> 4) * 4 + q;
                oh[(b * 1024 + row) * 512 + h * 64 + n0 + (lane & 15)] = t;
            }
        }
    }
}

// ---------------- K_G: out = oh @ W_out + b_out via MFMA (bf16 hi/lo, 3-term) ---------
__global__ __launch_bounds__(256) void k_out(const float* __restrict__ oh,
                                             const unsigned short* __restrict__ WoThi,
                                             const unsigned short* __restrict__ WoTlo,
                                             const float* __restrict__ bout,
                                             float* __restrict__ out) {
    __shared__ unsigned short ps[32 * 512];  // rows 0-15 hi, 16-31 lo; 32 KB
    int blk = blockIdx.x;                    // 512
    int cs = blk & 3;
    int rg = blk >> 2;                       // 128 row-groups
    int tid = threadIdx.x;
    int w = tid >> 6, lane = tid & 63;

    const float4* og = (const float4*)(oh + (size_t)rg * 16 * 512);
    #pragma unroll
    for (int rep = 0; rep < 8; ++rep) {
        int idx = rep * 256 + tid;           // 2048 float4 = 16 rows x 128
        int row = idx >> 7, c4 = idx & 127;
        float4 v = og[idx];
        int swz = (row & 7) << 3;
        int cbase = c4 * 4;
        ushort4v h4, l4;
        float vv[4] = {v.x, v.y, v.z, v.w};
        #pragma unroll
        for (int jj = 0; jj < 4; ++jj) {
            unsigned short hi = f2bf(vv[jj]);
            h4[jj] = hi;
            l4[jj] = f2bf(vv[jj] - bf2f(hi));
        }
        *(ushort4v*)(ps + row * 512 + (cbase ^ swz))        = h4;
        *(ushort4v*)(ps + (row + 16) * 512 + (cbase ^ swz)) = l4;
    }
    __syncthreads();

    int ar  = lane & 15;
    int asw = (ar & 7) << 3;
    int ak  = (lane >> 4) * 8;
    const unsigned short* aph = ps + ar * 512;
    const unsigned short* apl = ps + (ar + 16) * 512;
    int colb = cs * 128 + w * 32;
    size_t b0 = (size_t)(colb + ar) * 512 + ak;
    size_t b1 = b0 + 16 * 512;
    fvec4 acc0 = {0.f, 0.f, 0.f, 0.f};
    fvec4 acc1 = {0.f, 0.f, 0.f, 0.f};
    #pragma unroll 4
    for (int s = 0; s < 16; ++s) {
        int ko = s * 32 + ak;
        bfrag8 ahi = *(const bfrag8*)(aph + (ko ^ asw));
        bfrag8 alo = *(const bfrag8*)(apl + (ko ^ asw));
        bfrag8 bh0 = *(const bfrag8*)(WoThi + b0 + s * 32);
        bfrag8 bl0 = *(const bfrag8*)(WoTlo + b0 + s * 32);
        bfrag8 bh1 = *(const bfrag8*)(WoThi + b1 + s * 32);
        bfrag8 bl1 = *(const bfrag8*)(WoTlo + b1 + s * 32);
        acc0 = __builtin_amdgcn_mfma_f32_16x16x32_bf16(ahi, bh0, acc0, 0, 0, 0);
        acc0 = __builtin_amdgcn_mfma_f32_16x16x32_bf16(ahi, bl0, acc0, 0, 0, 0);
        acc0 = __builtin_amdgcn_mfma_f32_16x16x32_bf16(alo, bh0, acc0, 0, 0, 0);
        acc1 = __builtin_amdgcn_mfma_f32_16x16x32_bf16(ahi, bh1, acc1, 0, 0, 0);
        acc1 = __builtin_amdgcn_mfma_f32_16x16x32_bf16(ahi, bl1, acc1, 0, 0, 0);
        acc1 = __builtin_amdgcn_mfma_f32_16x16x32_bf16(alo, bh1, acc1, 0, 0, 0);
    }
    int rowb = rg * 16 + (lane >> 4) * 4;
    int col0 = colb + ar;
    float bias0 = bout[col0], bias1 = bout[col0 + 16];
    #pragma unroll
    for (int q = 0; q < 4; ++q) {
        out[(rowb + q) * 512 + col0]      = acc0[q] + bias0;
        out[(rowb + q) * 512 + col0 + 16] = acc1[q] + bias1;
    }
}

extern "C" void kernel_launch(void* const* d_in, const int* in_sizes, int n_in,
                              void* d_out, int out_size, void* d_ws, size_t ws_size,
                              hipStream_t stream) {
    const float* x     = (const float*)d_in[0];
    const float* Wqkv  = (const float*)d_in[1];
    const float* theta = (const float*)d_in[2];
    const float* Wout  = (const float*)d_in[3];
    const float* bout  = (const float*)d_in[4];

    float* out  = (float*)d_out;                  // [2,1024,512]
    float* attn = out + 2 * 1024 * 512;           // [2,8,1024,1024]

    float* ws  = (float*)d_ws;
    float* Wqp = ws;                               // 32768
    float* Wkp = ws + 32768;                       // 32768
    float* qp  = ws + 65536;                       // 131072
    float* kp  = ws + 196608;                      // 131072
    unsigned short* vThi = (unsigned short*)(ws + 327680);   // 1,048,576 u16
    unsigned short* vTlo = (unsigned short*)(ws + 851968);   // 1,048,576 u16
    float* oh   = ws + 1376256;                    // 1048576
    float* Wv   = ws + 2424832;                    // 262144
    unsigned short* WoThi = (unsigned short*)(ws + 2686976); // 262144 u16
    unsigned short* WoTlo = (unsigned short*)(ws + 2818048); // 262144 u16

    k_wproj   <<<128,  256, 0, stream>>>(Wqkv, theta, Wout, Wqp, Wkp, Wv, WoThi, WoTlo);
    k_proj    <<<1024, 512, 0, stream>>>(x, Wqp, Wkp, Wv, qp, kp, vThi, vTlo);
    k_attn_pv <<<2048, 512, 0, stream>>>(qp, kp, vThi, vTlo, attn, oh);
    k_out     <<<512,  256, 0, stream>>>(oh, WoThi, WoTlo, bout, out);
}

// Round 19
// 135.951 us; speedup vs baseline: 1.0248x; 1.0248x over previous
//
#include <hip/hip_runtime.h>
#include <hip/hip_bf16.h>

// Sizes (fixed): b=2, n=1024, dim=512, h=8, L=8, dh=64
// exp(-d2/T) with T=0.1 -> exp2(C*d2), C = -10*log2(e)
#define CEXP (-14.4269504088896340736f)

typedef __attribute__((ext_vector_type(8))) short bfrag8;   // 8 bf16 (4 VGPR) MFMA operand
typedef __attribute__((ext_vector_type(4))) float fvec4;    // MFMA accumulator / 16B vec
typedef __attribute__((ext_vector_type(8))) unsigned short ushort8;
typedef __attribute__((ext_vector_type(4))) unsigned short ushort4v;

__device__ inline unsigned short f2bf(float f) {            // RNE float->bf16
    unsigned u = __builtin_bit_cast(unsigned, f);
    u += 0x7fffu + ((u >> 16) & 1u);
    return (unsigned short)(u >> 16);
}
__device__ inline float bf2f(unsigned short h) {
    unsigned u = ((unsigned)h) << 16;
    return __builtin_bit_cast(float, u);
}

// Wave64 sum via DPP (rocPRIM pattern). ctrl/rmask immediates via template params.
template <int CTRL, int RMASK>
__device__ __forceinline__ float dpp_add(float v) {
    int m = __builtin_amdgcn_update_dpp(0, __builtin_bit_cast(int, v), CTRL, RMASK, 0xf, true);
    return v + __builtin_bit_cast(float, m);
}
__device__ __forceinline__ float wave_sum64(float v) {
    v = dpp_add<0xB1,  0xf>(v);   // quad_perm(1,0,3,2)
    v = dpp_add<0x4E,  0xf>(v);   // quad_perm(2,3,0,1)
    v = dpp_add<0x141, 0xf>(v);   // row_half_mirror
    v = dpp_add<0x140, 0xf>(v);   // row_mirror
    v = dpp_add<0x142, 0xa>(v);   // row_bcast15 into rows 1,3
    v = dpp_add<0x143, 0xc>(v);   // row_bcast31 into rows 2,3
    return __builtin_bit_cast(float, __builtin_amdgcn_readlane(__builtin_bit_cast(int, v), 63));
}

// ---------------- K_B: Wqp/Wkp projections; extract Wv; WoutT -> bf16 hi/lo ----------
__global__ __launch_bounds__(256) void k_wproj(const float* __restrict__ Wqkv,
                                               const float* __restrict__ theta,
                                               const float* __restrict__ Wout,
                                               float* __restrict__ Wqp,
                                               float* __restrict__ Wkp,
                                               float* __restrict__ Wv,
                                               unsigned short* __restrict__ WoThi,
                                               unsigned short* __restrict__ WoTlo) {
    __shared__ float th_s[64 * 65];
    __shared__ float ts2[64 * 65];
    int tid = threadIdx.x;
    int hl = tid & 63, cl = tid >> 6;
    #pragma unroll
    for (int i = 0; i < 16; ++i) {
        int r = cl * 16 + i;
        th_s[r * 65 + hl] = theta[r * 64 + hl];
    }
    __syncthreads();
    const float* ts = th_s + hl * 65;
    float ss = 0.f;
    #pragma unroll 8
    for (int d = 0; d < 64; ++d) ss = fmaf(ts[d], ts[d], ss);
    float inv = rsqrtf(ss);
    int c = blockIdx.x * 4 + cl;
    int h = hl >> 3;
    const float* wq = Wqkv + c * 1536 + h * 64;
    const float* wk = wq + 512;
    float aq = 0.f, ak = 0.f;
    #pragma unroll 4
    for (int d = 0; d < 64; ++d) {
        float tv = ts[d];
        aq = fmaf(wq[d], tv, aq);
        ak = fmaf(wk[d], tv, ak);
    }
    Wqp[c * 64 + hl] = aq * inv;
    Wkp[c * 64 + hl] = ak * inv;

    int c0b = blockIdx.x * 4;
    const float4* src = (const float4*)(Wqkv + 1024);
    float4* dst = (float4*)Wv;
    #pragma unroll
    for (int j = 0; j < 2; ++j) {
        int idx = j * 256 + tid;
        int cr = c0b + (idx >> 7), o4 = idx & 127;
        dst[cr * 128 + o4] = src[cr * 384 + o4];
    }

    // blocks 0..63: WoutT[n][c] = Wout[c][n] as bf16 hi/lo (64x64 tiles, LDS transpose)
    if (blockIdx.x < 64) {
        int r0 = (blockIdx.x >> 3) * 64;     // Wout row (= c of WoutT)
        int c0 = (blockIdx.x & 7) * 64;      // Wout col (= n of WoutT)
        int cc = tid & 63, rr = tid >> 6;
        #pragma unroll
        for (int k = 0; k < 16; ++k) {
            int r = rr + 4 * k;
            ts2[r * 65 + cc] = Wout[(r0 + r) * 512 + c0 + cc];
        }
        __syncthreads();
        int kk = tid & 63, nn = tid >> 6;    // kk = inner (coalesced) dim of WoutT
        #pragma unroll
        for (int i = 0; i < 16; ++i) {
            int n = nn + 4 * i;
            float v = ts2[kk * 65 + n];
            unsigned short hi = f2bf(v);
            WoThi[(size_t)(c0 + n) * 512 + r0 + kk] = hi;
            WoTlo[(size_t)(c0 + n) * 512 + r0 + kk] = f2bf(v - bf2f(hi));
        }
    }
}

// ---------------- K_C: qp/kp = scale * x @ W{q,k}p, layout [bh][l][n] ----------------
// 512 blocks x 4 rows; 512 thr = 128 cols (64 q + 64 k) x 4 K-quarters; LDS combine.
__global__ __launch_bounds__(512) void k_qkp(const float* __restrict__ x,
                                             const float* __restrict__ Wqp,
                                             const float* __restrict__ Wkp,
                                             float* __restrict__ qp,
                                             float* __restrict__ kp) {
    __shared__ float xs[4 * 512];            // 8 KB
    __shared__ float comb[4][128][4];        // 8 KB
    int tid = threadIdx.x;
    int i0 = blockIdx.x * 4;                 // 512 blocks
    const float4* xg = (const float4*)(x + i0 * 512);
    ((float4*)xs)[tid] = xg[tid];
    __syncthreads();

    int t  = tid & 127;
    int kh = tid >> 7;                       // 0..3
    int hl = t & 63;
    const float* Bm = (t & 64) ? Wkp : Wqp;
    float a[4] = {0.f, 0.f, 0.f, 0.f};
    int c4b = kh * 32;
    for (int c4 = c4b; c4 < c4b + 32; ++c4) {
        float b0 = Bm[(c4 * 4 + 0) * 64 + hl];
        float b1 = Bm[(c4 * 4 + 1) * 64 + hl];
        float b2 = Bm[(c4 * 4 + 2) * 64 + hl];
        float b3 = Bm[(c4 * 4 + 3) * 64 + hl];
        #pragma unroll
        for (int r = 0; r < 4; ++r) {
            float4 xv = *(const float4*)(xs + r * 512 + c4 * 4);
            a[r] = fmaf(xv.x, b0, fmaf(xv.y, b1, fmaf(xv.z, b2, fmaf(xv.w, b3, a[r]))));
        }
    }
    #pragma unroll
    for (int r = 0; r < 4; ++r) comb[kh][t][r] = a[r];
    __syncthreads();

    if (tid < 128) {
        int hl2 = tid & 63;
        int h = hl2 >> 3, l = hl2 & 7;
        float* dstp = (tid & 64) ? kp : qp;
        int b = i0 >> 10, i = i0 & 1023;
        fvec4 st;
        #pragma unroll
        for (int r = 0; r < 4; ++r)
            st[r] = (comb[0][tid][r] + comb[1][tid][r] + comb[2][tid][r] + comb[3][tid][r]) * 0.125f;
        *(fvec4*)(dstp + ((b * 8 + h) * 8 + l) * 1024 + i) = st;
    }
}

// ---------------- K_D: vT = (x @ Wv)^T as bf16 hi/lo, [bh][d][n] --------------------
// 512 blocks = 128 rowgroups(16 rows) x 4 col-slices(128); 256 thr = 128 cols x 2 K-halves.
// 16-row tiles halve Wv L2 traffic (256 -> 128 MB) vs 8-row tiles.
__global__ __launch_bounds__(256) void k_vproj(const float* __restrict__ x,
                                               const float* __restrict__ Wv,
                                               unsigned short* __restrict__ vThi,
                                               unsigned short* __restrict__ vTlo) {
    __shared__ float xs[16 * 512];           // 32 KB
    __shared__ float comb[2][128][16];       // 16 KB
    int tid = threadIdx.x;
    int blk = blockIdx.x;                    // 512
    int cs = blk & 3;
    int i0 = (blk >> 2) * 16;
    const float4* xg = (const float4*)(x + i0 * 512);
    float4* xs4 = (float4*)xs;
    #pragma unroll
    for (int j = 0; j < 8; ++j) xs4[j * 256 + tid] = xg[j * 256 + tid];
    __syncthreads();

    int t  = tid & 127;
    int kh = tid >> 7;                       // 0..1
    int col = cs * 128 + t;
    const float* wp = Wv + col;
    float a[16];
    #pragma unroll
    for (int r = 0; r < 16; ++r) a[r] = 0.f;
    int c4b = kh * 64;
    for (int c4 = c4b; c4 < c4b + 64; ++c4) {
        float w0 = wp[(c4 * 4 + 0) * 512];
        float w1 = wp[(c4 * 4 + 1) * 512];
        float w2 = wp[(c4 * 4 + 2) * 512];
        float w3 = wp[(c4 * 4 + 3) * 512];
        #pragma unroll
        for (int r = 0; r < 16; ++r) {
            float4 xv = *(const float4*)(xs + r * 512 + c4 * 4);
            a[r] = fmaf(xv.x, w0, fmaf(xv.y, w1, fmaf(xv.z, w2, fmaf(xv.w, w3, a[r]))));
        }
    }
    #pragma unroll
    for (int r = 0; r < 16; ++r) comb[kh][t][r] = a[r];
    __syncthreads();

    if (tid < 128) {
        int col2 = cs * 128 + tid;
        int h = col2 >> 6, d = col2 & 63;
        int b = i0 >> 10, ib = i0 & 1023;
        size_t off = (size_t)(b * 8 + h) * 65536 + (size_t)d * 1024 + ib;
        #pragma unroll
        for (int g = 0; g < 2; ++g) {        // rows g*8 .. g*8+7
            ushort8 vh, vl;
            #pragma unroll
            for (int r = 0; r < 8; ++r) {
                float v = comb[0][tid][g * 8 + r] + comb[1][tid][g * 8 + r];
                unsigned short hi = f2bf(v);
                vh[r] = hi;
                vl[r] = f2bf(v - bf2f(hi));
            }
            *(ushort8*)(vThi + off + g * 8) = vh;
            *(ushort8*)(vTlo + off + g * 8) = vl;
        }
    }
}

// ---------------- K_E: fused attention rows + MFMA PV; 512 thr / 8 waves --------------
// r17-exact (proven ~76 us): XCD-aware bh mapping, b128 LDS reads, packed-f32 math, NT stores.
__global__ __launch_bounds__(512) void k_attn_pv(const float* __restrict__ qp,
                                                 const float* __restrict__ kp,
                                                 const unsigned short* __restrict__ vThi,
                                                 const unsigned short* __restrict__ vTlo,
                                                 float* __restrict__ attn,
                                                 float* __restrict__ oh) {
    __shared__ float s_buf[8 * 1024];        // kp (f32) phase 1; P hi/lo bf16 [16][1024] phase 2
    __shared__ float sc[4 * 64 * 4];         // 4 KB split-K combine scratch
    int bx = blockIdx.x;                     // 2048
    int idx = bx >> 3;                       // [0,256)
    int bh = (bx & 7) * 2 + (idx >> 7);      // XCD-aware: 2 bh per XCD -> L2-resident vT
    int rowbase = (idx & 127) * 8;
    int tid = threadIdx.x;
    int w = tid >> 6, lane = tid & 63;

    const float4* kp4 = (const float4*)(kp + bh * 8192);
    float4* kps4 = (float4*)s_buf;
    #pragma unroll
    for (int k = 0; k < 4; ++k) kps4[k * 512 + tid] = kp4[k * 512 + tid];

    int r = rowbase + w;
    float qv[8];
    #pragma unroll
    for (int l = 0; l < 8; ++l) qv[l] = qp[bh * 8192 + l * 1024 + r];
    __syncthreads();

    const fvec4 CE4 = {CEXP, CEXP, CEXP, CEXP};
    fvec4 acc4[4];
    #pragma unroll
    for (int mm = 0; mm < 4; ++mm) acc4[mm] = (fvec4){0.f, 0.f, 0.f, 0.f};

    for (int l = 0; l < 8; ++l) {
        fvec4 kv4[4], e4[4];
        #pragma unroll
        for (int mm = 0; mm < 4; ++mm)
            kv4[mm] = *(const fvec4*)(s_buf + l * 1024 + mm * 256 + lane * 4);
        float sqs = -2.f * CEXP * qv[l];
        fvec4 sq4 = {sqs, sqs, sqs, sqs};
        fvec4 sum4 = {0.f, 0.f, 0.f, 0.f};
        #pragma unroll
        for (int mm = 0; mm < 4; ++mm) {
            fvec4 k2 = (kv4[mm] * kv4[mm]) * CE4;
            fvec4 t  = sq4 * kv4[mm] + k2;
            fvec4 e;
            e[0] = __builtin_amdgcn_exp2f(t[0]);
            e[1] = __builtin_amdgcn_exp2f(t[1]);
            e[2] = __builtin_amdgcn_exp2f(t[2]);
            e[3] = __builtin_amdgcn_exp2f(t[3]);
            e4[mm] = e;
            sum4 += e;
        }
        float s = (sum4[0] + sum4[1]) + (sum4[2] + sum4[3]);
        float inv = 0.125f * __builtin_amdgcn_rcpf(wave_sum64(s));
        fvec4 inv4 = {inv, inv, inv, inv};
        #pragma unroll
        for (int mm = 0; mm < 4; ++mm) acc4[mm] = e4[mm] * inv4 + acc4[mm];
    }

    __syncthreads();   // all waves done reading kp from s_buf

    unsigned short* ps = (unsigned short*)s_buf;
    int swz = w << 3;
    #pragma unroll
    for (int mm = 0; mm < 4; ++mm) {
        ushort4v h4, l4;
        #pragma unroll
        for (int jj = 0; jj < 4; ++jj) {
            float v = acc4[mm][jj];
            unsigned short hi = f2bf(v);
            h4[jj] = hi;
            l4[jj] = f2bf(v - bf2f(hi));
        }
        int j0 = mm * 256 + lane * 4;
        *(ushort4v*)(ps + w * 1024 + (j0 ^ swz))       = h4;
        *(ushort4v*)(ps + (w + 8) * 1024 + (j0 ^ swz)) = l4;
    }
    __syncthreads();

    float* aR = attn + ((size_t)(bh * 1024 + r)) * 1024;
    #pragma unroll
    for (int mm = 0; mm < 4; ++mm)
        __builtin_nontemporal_store(acc4[mm], (fvec4*)(aR + mm * 256 + lane * 4));

    // Phase 2: wave w -> cols n0..n0+15, K-half kh; pairs (w, w+4) combine via LDS.
    int n0 = (w & 3) * 16;
    int kh = w >> 2;
    int ar  = lane & 15;
    int asw = (ar & 7) << 3;
    int ak  = (lane >> 4) * 8;
    const unsigned short* ap = ps + ar * 1024;
    size_t boff = (size_t)bh * 65536 + (size_t)(n0 + (lane & 15)) * 1024 + ak;
    const unsigned short* bh_p = vThi + boff;
    const unsigned short* bl_p = vTlo + boff;
    fvec4 c2 = {0.f, 0.f, 0.f, 0.f};
    #pragma unroll 4
    for (int s = kh * 16; s < kh * 16 + 16; ++s) {
        bfrag8 a  = *(const bfrag8*)(ap + ((s * 32 + ak) ^ asw));
        bfrag8 vh = *(const bfrag8*)(bh_p + s * 32);
        bfrag8 vl = *(const bfrag8*)(bl_p + s * 32);
        c2 = __builtin_amdgcn_mfma_f32_16x16x32_bf16(a, vh, c2, 0, 0, 0);
        c2 = __builtin_amdgcn_mfma_f32_16x16x32_bf16(a, vl, c2, 0, 0, 0);
    }
    if (w >= 4) {
        #pragma unroll
        for (int q = 0; q < 4; ++q) sc[(w - 4) * 256 + lane * 4 + q] = c2[q];
    }
    __syncthreads();
    if (w < 4) {
        int b = bh >> 3, h = bh & 7;
        #pragma unroll
        for (int q = 0; q < 4; ++q) {
            float t = c2[q] + sc[w * 256 + lane * 4 + q];
            t += __shfl_xor(t, 32);               // hi row + lo row
            if (lane < 32) {
                int row = rowbase + (lane >> 4) * 4 + q;
                oh[(b * 1024 + row) * 512 + h * 64 + n0 + (lane & 15)] = t;
            }
        }
    }
}

// ---------------- K_G: out = oh @ W_out + b_out via MFMA (bf16 hi/lo, 3-term) ---------
__global__ __launch_bounds__(256) void k_out(const float* __restrict__ oh,
                                             const unsigned short* __restrict__ WoThi,
                                             const unsigned short* __restrict__ WoTlo,
                                             const float* __restrict__ bout,
                                             float* __restrict__ out) {
    __shared__ unsigned short ps[32 * 512];  // rows 0-15 hi, 16-31 lo; 32 KB
    int blk = blockIdx.x;                    // 512
    int cs = blk & 3;
    int rg = blk >> 2;                       // 128 row-groups
    int tid = threadIdx.x;
    int w = tid >> 6, lane = tid & 63;

    const float4* og = (const float4*)(oh + (size_t)rg * 16 * 512);
    #pragma unroll
    for (int rep = 0; rep < 8; ++rep) {
        int idx = rep * 256 + tid;           // 2048 float4 = 16 rows x 128
        int row = idx >> 7, c4 = idx & 127;
        float4 v = og[idx];
        int swz = (row & 7) << 3;
        int cbase = c4 * 4;
        ushort4v h4, l4;
        float vv[4] = {v.x, v.y, v.z, v.w};
        #pragma unroll
        for (int jj = 0; jj < 4; ++jj) {
            unsigned short hi = f2bf(vv[jj]);
            h4[jj] = hi;
            l4[jj] = f2bf(vv[jj] - bf2f(hi));
        }
        *(ushort4v*)(ps + row * 512 + (cbase ^ swz))        = h4;
        *(ushort4v*)(ps + (row + 16) * 512 + (cbase ^ swz)) = l4;
    }
    __syncthreads();

    int ar  = lane & 15;
    int asw = (ar & 7) << 3;
    int ak  = (lane >> 4) * 8;
    const unsigned short* aph = ps + ar * 512;
    const unsigned short* apl = ps + (ar + 16) * 512;
    int colb = cs * 128 + w * 32;
    size_t b0 = (size_t)(colb + ar) * 512 + ak;
    size_t b1 = b0 + 16 * 512;
    fvec4 acc0 = {0.f, 0.f, 0.f, 0.f};
    fvec4 acc1 = {0.f, 0.f, 0.f, 0.f};
    #pragma unroll 4
    for (int s = 0; s < 16; ++s) {
        int ko = s * 32 + ak;
        bfrag8 ahi = *(const bfrag8*)(aph + (ko ^ asw));
        bfrag8 alo = *(const bfrag8*)(apl + (ko ^ asw));
        bfrag8 bh0 = *(const bfrag8*)(WoThi + b0 + s * 32);
        bfrag8 bl0 = *(const bfrag8*)(WoTlo + b0 + s * 32);
        bfrag8 bh1 = *(const bfrag8*)(WoThi + b1 + s * 32);
        bfrag8 bl1 = *(const bfrag8*)(WoTlo + b1 + s * 32);
        acc0 = __builtin_amdgcn_mfma_f32_16x16x32_bf16(ahi, bh0, acc0, 0, 0, 0);
        acc0 = __builtin_amdgcn_mfma_f32_16x16x32_bf16(ahi, bl0, acc0, 0, 0, 0);
        acc0 = __builtin_amdgcn_mfma_f32_16x16x32_bf16(alo, bh0, acc0, 0, 0, 0);
        acc1 = __builtin_amdgcn_mfma_f32_16x16x32_bf16(ahi, bh1, acc1, 0, 0, 0);
        acc1 = __builtin_amdgcn_mfma_f32_16x16x32_bf16(ahi, bl1, acc1, 0, 0, 0);
        acc1 = __builtin_amdgcn_mfma_f32_16x16x32_bf16(alo, bh1, acc1, 0, 0, 0);
    }
    int rowb = rg * 16 + (lane >> 4) * 4;
    int col0 = colb + ar;
    float bias0 = bout[col0], bias1 = bout[col0 + 16];
    #pragma unroll
    for (int q = 0; q < 4; ++q) {
        out[(rowb + q) * 512 + col0]      = acc0[q] + bias0;
        out[(rowb + q) * 512 + col0 + 16] = acc1[q] + bias1;
    }
}

extern "C" void kernel_launch(void* const* d_in, const int* in_sizes, int n_in,
                              void* d_out, int out_size, void* d_ws, size_t ws_size,
                              hipStream_t stream) {
    const float* x     = (const float*)d_in[0];
    const float* Wqkv  = (const float*)d_in[1];
    const float* theta = (const float*)d_in[2];
    const float* Wout  = (const float*)d_in[3];
    const float* bout  = (const float*)d_in[4];

    float* out  = (float*)d_out;                  // [2,1024,512]
    float* attn = out + 2 * 1024 * 512;           // [2,8,1024,1024]

    float* ws  = (float*)d_ws;
    float* Wqp = ws;                               // 32768
    float* Wkp = ws + 32768;                       // 32768
    float* qp  = ws + 65536;                       // 131072
    float* kp  = ws + 196608;                      // 131072
    unsigned short* vThi = (unsigned short*)(ws + 327680);   // 1,048,576 u16
    unsigned short* vTlo = (unsigned short*)(ws + 851968);   // 1,048,576 u16
    float* oh   = ws + 1376256;                    // 1048576
    float* Wv   = ws + 2424832;                    // 262144
    unsigned short* WoThi = (unsigned short*)(ws + 2686976); // 262144 u16
    unsigned short* WoTlo = (unsigned short*)(ws + 2818048); // 262144 u16

    k_wproj   <<<128,  256, 0, stream>>>(Wqkv, theta, Wout, Wqp, Wkp, Wv, WoThi, WoTlo);
    k_qkp     <<<512,  512, 0, stream>>>(x, Wqp, Wkp, qp, kp);
    k_vproj   <<<512,  256, 0, stream>>>(x, Wv, vThi, vTlo);
    k_attn_pv <<<2048, 512, 0, stream>>>(qp, kp, vThi, vTlo, attn, oh);
    k_out     <<<512,  256, 0, stream>>>(oh, WoThi, WoTlo, bout, out);
}

// Round 20
// 131.692 us; speedup vs baseline: 1.0579x; 1.0323x over previous
//
#include <hip/hip_runtime.h>
#include <hip/hip_bf16.h>

// Sizes (fixed): b=2, n=1024, dim=512, h=8, L=8, dh=64
// exp(-d2/T) with T=0.1 -> exp2(C*d2), C = -10*log2(e)
#define CEXP (-14.4269504088896340736f)

typedef __attribute__((ext_vector_type(8))) short bfrag8;   // 8 bf16 (4 VGPR) MFMA operand
typedef __attribute__((ext_vector_type(4))) float fvec4;    // MFMA accumulator / 16B vec
typedef __attribute__((ext_vector_type(8))) unsigned short ushort8;
typedef __attribute__((ext_vector_type(4))) unsigned short ushort4v;

__device__ inline unsigned short f2bf(float f) {            // RNE float->bf16
    unsigned u = __builtin_bit_cast(unsigned, f);
    u += 0x7fffu + ((u >> 16) & 1u);
    return (unsigned short)(u >> 16);
}
__device__ inline float bf2f(unsigned short h) {
    unsigned u = ((unsigned)h) << 16;
    return __builtin_bit_cast(float, u);
}

// Wave64 sum via DPP (rocPRIM pattern). ctrl/rmask immediates via template params.
template <int CTRL, int RMASK>
__device__ __forceinline__ float dpp_add(float v) {
    int m = __builtin_amdgcn_update_dpp(0, __builtin_bit_cast(int, v), CTRL, RMASK, 0xf, true);
    return v + __builtin_bit_cast(float, m);
}
__device__ __forceinline__ float wave_sum64(float v) {
    v = dpp_add<0xB1,  0xf>(v);   // quad_perm(1,0,3,2)
    v = dpp_add<0x4E,  0xf>(v);   // quad_perm(2,3,0,1)
    v = dpp_add<0x141, 0xf>(v);   // row_half_mirror
    v = dpp_add<0x140, 0xf>(v);   // row_mirror
    v = dpp_add<0x142, 0xa>(v);   // row_bcast15 into rows 1,3
    v = dpp_add<0x143, 0xc>(v);   // row_bcast31 into rows 2,3
    return __builtin_bit_cast(float, __builtin_amdgcn_readlane(__builtin_bit_cast(int, v), 63));
}

// ---------------- K_B: Wqp/Wkp; extract Wv; WoutT hi/lo; x -> bf16 hi/lo split --------
__global__ __launch_bounds__(256) void k_wproj(const float* __restrict__ Wqkv,
                                               const float* __restrict__ theta,
                                               const float* __restrict__ Wout,
                                               const float* __restrict__ x,
                                               float* __restrict__ Wqp,
                                               float* __restrict__ Wkp,
                                               float* __restrict__ Wv,
                                               unsigned short* __restrict__ WoThi,
                                               unsigned short* __restrict__ WoTlo,
                                               unsigned short* __restrict__ xhi,
                                               unsigned short* __restrict__ xlo) {
    __shared__ float th_s[64 * 65];
    __shared__ float ts2[64 * 65];
    int tid = threadIdx.x;
    int hl = tid & 63, cl = tid >> 6;
    #pragma unroll
    for (int i = 0; i < 16; ++i) {
        int r = cl * 16 + i;
        th_s[r * 65 + hl] = theta[r * 64 + hl];
    }
    __syncthreads();
    const float* ts = th_s + hl * 65;
    float ss = 0.f;
    #pragma unroll 8
    for (int d = 0; d < 64; ++d) ss = fmaf(ts[d], ts[d], ss);
    float inv = rsqrtf(ss);
    int c = blockIdx.x * 4 + cl;
    int h = hl >> 3;
    const float* wq = Wqkv + c * 1536 + h * 64;
    const float* wk = wq + 512;
    float aq = 0.f, ak = 0.f;
    #pragma unroll 4
    for (int d = 0; d < 64; ++d) {
        float tv = ts[d];
        aq = fmaf(wq[d], tv, aq);
        ak = fmaf(wk[d], tv, ak);
    }
    Wqp[c * 64 + hl] = aq * inv;
    Wkp[c * 64 + hl] = ak * inv;

    // extract Wv (contiguous f32)
    int c0b = blockIdx.x * 4;
    const float4* src = (const float4*)(Wqkv + 1024);
    float4* dst = (float4*)Wv;
    #pragma unroll
    for (int j = 0; j < 2; ++j) {
        int idx = j * 256 + tid;
        int cr = c0b + (idx >> 7), o4 = idx & 127;
        dst[cr * 128 + o4] = src[cr * 384 + o4];
    }

    // x split: 128 blocks x 8192 floats -> xhi/xlo bf16
    {
        const float4* x4 = (const float4*)x;
        int base4 = blockIdx.x * 2048;
        #pragma unroll
        for (int j = 0; j < 8; ++j) {
            int idx = base4 + j * 256 + tid;
            float4 v = x4[idx];
            float vv[4] = {v.x, v.y, v.z, v.w};
            ushort4v h4, l4;
            #pragma unroll
            for (int jj = 0; jj < 4; ++jj) {
                unsigned short hi = f2bf(vv[jj]);
                h4[jj] = hi;
                l4[jj] = f2bf(vv[jj] - bf2f(hi));
            }
            *(ushort4v*)(xhi + (size_t)idx * 4) = h4;
            *(ushort4v*)(xlo + (size_t)idx * 4) = l4;
        }
    }

    // blocks 0..63: WoutT[n][c] = Wout[c][n] as bf16 hi/lo (64x64 tiles, LDS transpose)
    if (blockIdx.x < 64) {
        int r0 = (blockIdx.x >> 3) * 64;
        int c0 = (blockIdx.x & 7) * 64;
        int cc = tid & 63, rr = tid >> 6;
        #pragma unroll
        for (int k = 0; k < 16; ++k) {
            int r = rr + 4 * k;
            ts2[r * 65 + cc] = Wout[(r0 + r) * 512 + c0 + cc];
        }
        __syncthreads();
        int kk = tid & 63, nn = tid >> 6;
        #pragma unroll
        for (int i = 0; i < 16; ++i) {
            int n = nn + 4 * i;
            float v = ts2[kk * 65 + n];
            unsigned short hi = f2bf(v);
            WoThi[(size_t)(c0 + n) * 512 + r0 + kk] = hi;
            WoTlo[(size_t)(c0 + n) * 512 + r0 + kk] = f2bf(v - bf2f(hi));
        }
    }
}

// ---------------- K_B2: WallT[n][k] (n: 0-63 Wqp, 64-127 Wkp, 128-639 Wv) bf16 hi/lo --
__global__ __launch_bounds__(256) void k_wsplit(const float* __restrict__ Wqp,
                                                const float* __restrict__ Wkp,
                                                const float* __restrict__ Wv,
                                                unsigned short* __restrict__ WThi,
                                                unsigned short* __restrict__ WTlo) {
    __shared__ float ts[64 * 65];
    int blk = blockIdx.x;                    // 80
    const float* src;
    int ld, k0, nbase;
    if (blk < 8)       { src = Wqp + blk * 64 * 64;       ld = 64;  k0 = blk * 64;       nbase = 0; }
    else if (blk < 16) { src = Wkp + (blk - 8) * 64 * 64; ld = 64;  k0 = (blk - 8) * 64; nbase = 64; }
    else {
        int t = blk - 16, kt = t >> 3, nt = t & 7;
        src = Wv + kt * 64 * 512 + nt * 64;  ld = 512; k0 = kt * 64; nbase = 128 + nt * 64;
    }
    int tid = threadIdx.x;
    int cc = tid & 63, rr = tid >> 6;
    #pragma unroll
    for (int k = 0; k < 16; ++k) {
        int r = rr + 4 * k;
        ts[r * 65 + cc] = src[r * ld + cc];  // ts[k_local][n_local]
    }
    __syncthreads();
    int kk = tid & 63, nn = tid >> 6;
    #pragma unroll
    for (int i = 0; i < 16; ++i) {
        int n = nn + 4 * i;
        float v = ts[kk * 65 + n];
        unsigned short hi = f2bf(v);
        WThi[(size_t)(nbase + n) * 512 + k0 + kk] = hi;
        WTlo[(size_t)(nbase + n) * 512 + k0 + kk] = f2bf(v - bf2f(hi));
    }
}

// ---------------- K_P: mega projection GEMM via MFMA: [qp|kp|vT] = x @ WallT^T --------
// 640 blocks = 128 rowgroups(16 rows) x 5 col-slices(128); 256 thr / 4 waves;
// wave = 32 cols (2 tiles); A = xhi/xlo staged in swizzled LDS; 3-term hi/lo MFMA.
__global__ __launch_bounds__(256) void k_proj(const unsigned short* __restrict__ xhi,
                                              const unsigned short* __restrict__ xlo,
                                              const unsigned short* __restrict__ WThi,
                                              const unsigned short* __restrict__ WTlo,
                                              float* __restrict__ qp,
                                              float* __restrict__ kp,
                                              unsigned short* __restrict__ vThi,
                                              unsigned short* __restrict__ vTlo) {
    __shared__ unsigned short ps[32 * 512];  // rows 0-15 hi, 16-31 lo; 32 KB
    int blk = blockIdx.x;                    // 640
    int cs = blk % 5;
    int rg = blk / 5;                        // 128 rowgroups
    int tid = threadIdx.x;
    int w = tid >> 6, lane = tid & 63;

    const ushort8* xh8 = (const ushort8*)(xhi + (size_t)rg * 16 * 512);
    const ushort8* xl8 = (const ushort8*)(xlo + (size_t)rg * 16 * 512);
    #pragma unroll
    for (int rep = 0; rep < 4; ++rep) {
        int idx = rep * 256 + tid;           // 1024 = 16 rows x 64 chunks
        int row = idx >> 6, c8 = (idx & 63) * 8;
        int swz = (row & 7) << 3;
        *(ushort8*)(ps + row * 512 + (c8 ^ swz))        = xh8[idx];
        *(ushort8*)(ps + (row + 16) * 512 + (c8 ^ swz)) = xl8[idx];
    }
    __syncthreads();

    int ar  = lane & 15;
    int asw = (ar & 7) << 3;
    int ak  = (lane >> 4) * 8;
    const unsigned short* aph = ps + ar * 512;
    const unsigned short* apl = ps + (ar + 16) * 512;
    int colb = cs * 128 + w * 32;
    size_t b0 = (size_t)(colb + ar) * 512 + ak;
    size_t b1 = b0 + 16 * 512;
    fvec4 acc0 = {0.f, 0.f, 0.f, 0.f};
    fvec4 acc1 = {0.f, 0.f, 0.f, 0.f};
    #pragma unroll 4
    for (int s = 0; s < 16; ++s) {
        int ko = s * 32 + ak;
        bfrag8 ahi = *(const bfrag8*)(aph + (ko ^ asw));
        bfrag8 alo = *(const bfrag8*)(apl + (ko ^ asw));
        bfrag8 bh0 = *(const bfrag8*)(WThi + b0 + s * 32);
        bfrag8 bl0 = *(const bfrag8*)(WTlo + b0 + s * 32);
        bfrag8 bh1 = *(const bfrag8*)(WThi + b1 + s * 32);
        bfrag8 bl1 = *(const bfrag8*)(WTlo + b1 + s * 32);
        acc0 = __builtin_amdgcn_mfma_f32_16x16x32_bf16(ahi, bh0, acc0, 0, 0, 0);
        acc0 = __builtin_amdgcn_mfma_f32_16x16x32_bf16(ahi, bl0, acc0, 0, 0, 0);
        acc0 = __builtin_amdgcn_mfma_f32_16x16x32_bf16(alo, bh0, acc0, 0, 0, 0);
        acc1 = __builtin_amdgcn_mfma_f32_16x16x32_bf16(ahi, bh1, acc1, 0, 0, 0);
        acc1 = __builtin_amdgcn_mfma_f32_16x16x32_bf16(ahi, bl1, acc1, 0, 0, 0);
        acc1 = __builtin_amdgcn_mfma_f32_16x16x32_bf16(alo, bh1, acc1, 0, 0, 0);
    }

    int rowb = rg * 16 + (lane >> 4) * 4;
    int b = rowb >> 10, n = rowb & 1023;
    fvec4 accs[2] = {acc0, acc1};
    #pragma unroll
    for (int t = 0; t < 2; ++t) {
        int col = colb + t * 16 + ar;
        fvec4 a = accs[t];
        if (col < 128) {
            // qp/kp: scale 0.125; layout [(b*8+h)*8+l][n], 4 consecutive n -> float4
            int hl = col & 63;
            float* dstp = (col < 64) ? qp : kp;
            fvec4 st;
            st[0] = a[0] * 0.125f; st[1] = a[1] * 0.125f;
            st[2] = a[2] * 0.125f; st[3] = a[3] * 0.125f;
            *(fvec4*)(dstp + ((size_t)((b * 8 + (hl >> 3)) * 8 + (hl & 7))) * 1024 + n) = st;
        } else {
            // vT: bf16 hi/lo, layout [(b*8+h)][d][n]
            int vcol = col - 128;
            int h = vcol >> 6, d = vcol & 63;
            ushort4v h4, l4;
            #pragma unroll
            for (int q = 0; q < 4; ++q) {
                unsigned short hi = f2bf(a[q]);
                h4[q] = hi;
                l4[q] = f2bf(a[q] - bf2f(hi));
            }
            size_t off = (size_t)(b * 8 + h) * 65536 + (size_t)d * 1024 + n;
            *(ushort4v*)(vThi + off) = h4;
            *(ushort4v*)(vTlo + off) = l4;
        }
    }
}

// ---------------- K_E: fused attention rows + MFMA PV; 512 thr / 8 waves (r17 exact) --
__global__ __launch_bounds__(512) void k_attn_pv(const float* __restrict__ qp,
                                                 const float* __restrict__ kp,
                                                 const unsigned short* __restrict__ vThi,
                                                 const unsigned short* __restrict__ vTlo,
                                                 float* __restrict__ attn,
                                                 float* __restrict__ oh) {
    __shared__ float s_buf[8 * 1024];        // kp (f32) phase 1; P hi/lo bf16 [16][1024] phase 2
    __shared__ float sc[4 * 64 * 4];         // 4 KB split-K combine scratch
    int bx = blockIdx.x;                     // 2048
    int idx = bx >> 3;                       // [0,256)
    int bh = (bx & 7) * 2 + (idx >> 7);      // XCD-aware: 2 bh per XCD -> L2-resident vT
    int rowbase = (idx & 127) * 8;
    int tid = threadIdx.x;
    int w = tid >> 6, lane = tid & 63;

    const float4* kp4 = (const float4*)(kp + bh * 8192);
    float4* kps4 = (float4*)s_buf;
    #pragma unroll
    for (int k = 0; k < 4; ++k) kps4[k * 512 + tid] = kp4[k * 512 + tid];

    int r = rowbase + w;
    float qv[8];
    #pragma unroll
    for (int l = 0; l < 8; ++l) qv[l] = qp[bh * 8192 + l * 1024 + r];
    __syncthreads();

    const fvec4 CE4 = {CEXP, CEXP, CEXP, CEXP};
    fvec4 acc4[4];
    #pragma unroll
    for (int mm = 0; mm < 4; ++mm) acc4[mm] = (fvec4){0.f, 0.f, 0.f, 0.f};

    for (int l = 0; l < 8; ++l) {
        fvec4 kv4[4], e4[4];
        #pragma unroll
        for (int mm = 0; mm < 4; ++mm)
            kv4[mm] = *(const fvec4*)(s_buf + l * 1024 + mm * 256 + lane * 4);
        float sqs = -2.f * CEXP * qv[l];
        fvec4 sq4 = {sqs, sqs, sqs, sqs};
        fvec4 sum4 = {0.f, 0.f, 0.f, 0.f};
        #pragma unroll
        for (int mm = 0; mm < 4; ++mm) {
            fvec4 k2 = (kv4[mm] * kv4[mm]) * CE4;
            fvec4 t  = sq4 * kv4[mm] + k2;
            fvec4 e;
            e[0] = __builtin_amdgcn_exp2f(t[0]);
            e[1] = __builtin_amdgcn_exp2f(t[1]);
            e[2] = __builtin_amdgcn_exp2f(t[2]);
            e[3] = __builtin_amdgcn_exp2f(t[3]);
            e4[mm] = e;
            sum4 += e;
        }
        float s = (sum4[0] + sum4[1]) + (sum4[2] + sum4[3]);
        float inv = 0.125f * __builtin_amdgcn_rcpf(wave_sum64(s));
        fvec4 inv4 = {inv, inv, inv, inv};
        #pragma unroll
        for (int mm = 0; mm < 4; ++mm) acc4[mm] = e4[mm] * inv4 + acc4[mm];
    }

    __syncthreads();   // all waves done reading kp from s_buf

    unsigned short* ps = (unsigned short*)s_buf;
    int swz = w << 3;
    #pragma unroll
    for (int mm = 0; mm < 4; ++mm) {
        ushort4v h4, l4;
        #pragma unroll
        for (int jj = 0; jj < 4; ++jj) {
            float v = acc4[mm][jj];
            unsigned short hi = f2bf(v);
            h4[jj] = hi;
            l4[jj] = f2bf(v - bf2f(hi));
        }
        int j0 = mm * 256 + lane * 4;
        *(ushort4v*)(ps + w * 1024 + (j0 ^ swz))       = h4;
        *(ushort4v*)(ps + (w + 8) * 1024 + (j0 ^ swz)) = l4;
    }
    __syncthreads();

    float* aR = attn + ((size_t)(bh * 1024 + r)) * 1024;
    #pragma unroll
    for (int mm = 0; mm < 4; ++mm)
        __builtin_nontemporal_store(acc4[mm], (fvec4*)(aR + mm * 256 + lane * 4));

    // Phase 2: wave w -> cols n0..n0+15, K-half kh; pairs (w, w+4) combine via LDS.
    int n0 = (w & 3) * 16;
    int kh = w >> 2;
    int ar  = lane & 15;
    int asw = (ar & 7) << 3;
    int ak  = (lane >> 4) * 8;
    const unsigned short* ap = ps + ar * 1024;
    size_t boff = (size_t)bh * 65536 + (size_t)(n0 + (lane & 15)) * 1024 + ak;
    const unsigned short* bh_p = vThi + boff;
    const unsigned short* bl_p = vTlo + boff;
    fvec4 c2 = {0.f, 0.f, 0.f, 0.f};
    #pragma unroll 4
    for (int s = kh * 16; s < kh * 16 + 16; ++s) {
        bfrag8 a  = *(const bfrag8*)(ap + ((s * 32 + ak) ^ asw));
        bfrag8 vh = *(const bfrag8*)(bh_p + s * 32);
        bfrag8 vl = *(const bfrag8*)(bl_p + s * 32);
        c2 = __builtin_amdgcn_mfma_f32_16x16x32_bf16(a, vh, c2, 0, 0, 0);
        c2 = __builtin_amdgcn_mfma_f32_16x16x32_bf16(a, vl, c2, 0, 0, 0);
    }
    if (w >= 4) {
        #pragma unroll
        for (int q = 0; q < 4; ++q) sc[(w - 4) * 256 + lane * 4 + q] = c2[q];
    }
    __syncthreads();
    if (w < 4) {
        int b = bh >> 3, h = bh & 7;
        #pragma unroll
        for (int q = 0; q < 4; ++q) {
            float t = c2[q] + sc[w * 256 + lane * 4 + q];
            t += __shfl_xor(t, 32);               // hi row + lo row
            if (lane < 32) {
                int row = rowbase + (lane >> 4) * 4 + q;
                oh[(b * 1024 + row) * 512 + h * 64 + n0 + (lane & 15)] = t;
            }
        }
    }
}

// ---------------- K_G: out = oh @ W_out + b_out via MFMA (bf16 hi/lo, 3-term) ---------
__global__ __launch_bounds__(256) void k_out(const float* __restrict__ oh,
                                             const unsigned short* __restrict__ WoThi,
                                             const unsigned short* __restrict__ WoTlo,
                                             const float* __restrict__ bout,
                                             float* __restrict__ out) {
    __shared__ unsigned short ps[32 * 512];  // rows 0-15 hi, 16-31 lo; 32 KB
    int blk = blockIdx.x;                    // 512
    int cs = blk & 3;
    int rg = blk >> 2;                       // 128 row-groups
    int tid = threadIdx.x;
    int w = tid >> 6, lane = tid & 63;

    const float4* og = (const float4*)(oh + (size_t)rg * 16 * 512);
    #pragma unroll
    for (int rep = 0; rep < 8; ++rep) {
        int idx = rep * 256 + tid;           // 2048 float4 = 16 rows x 128
        int row = idx >> 7, c4 = idx & 127;
        float4 v = og[idx];
        int swz = (row & 7) << 3;
        int cbase = c4 * 4;
        ushort4v h4, l4;
        float vv[4] = {v.x, v.y, v.z, v.w};
        #pragma unroll
        for (int jj = 0; jj < 4; ++jj) {
            unsigned short hi = f2bf(vv[jj]);
            h4[jj] = hi;
            l4[jj] = f2bf(vv[jj] - bf2f(hi));
        }
        *(ushort4v*)(ps + row * 512 + (cbase ^ swz))        = h4;
        *(ushort4v*)(ps + (row + 16) * 512 + (cbase ^ swz)) = l4;
    }
    __syncthreads();

    int ar  = lane & 15;
    int asw = (ar & 7) << 3;
    int ak  = (lane >> 4) * 8;
    const unsigned short* aph = ps + ar * 512;
    const unsigned short* apl = ps + (ar + 16) * 512;
    int colb = cs * 128 + w * 32;
    size_t b0 = (size_t)(colb + ar) * 512 + ak;
    size_t b1 = b0 + 16 * 512;
    fvec4 acc0 = {0.f, 0.f, 0.f, 0.f};
    fvec4 acc1 = {0.f, 0.f, 0.f, 0.f};
    #pragma unroll 4
    for (int s = 0; s < 16; ++s) {
        int ko = s * 32 + ak;
        bfrag8 ahi = *(const bfrag8*)(aph + (ko ^ asw));
        bfrag8 alo = *(const bfrag8*)(apl + (ko ^ asw));
        bfrag8 bh0 = *(const bfrag8*)(WoThi + b0 + s * 32);
        bfrag8 bl0 = *(const bfrag8*)(WoTlo + b0 + s * 32);
        bfrag8 bh1 = *(const bfrag8*)(WoThi + b1 + s * 32);
        bfrag8 bl1 = *(const bfrag8*)(WoTlo + b1 + s * 32);
        acc0 = __builtin_amdgcn_mfma_f32_16x16x32_bf16(ahi, bh0, acc0, 0, 0, 0);
        acc0 = __builtin_amdgcn_mfma_f32_16x16x32_bf16(ahi, bl0, acc0, 0, 0, 0);
        acc0 = __builtin_amdgcn_mfma_f32_16x16x32_bf16(alo, bh0, acc0, 0, 0, 0);
        acc1 = __builtin_amdgcn_mfma_f32_16x16x32_bf16(ahi, bh1, acc1, 0, 0, 0);
        acc1 = __builtin_amdgcn_mfma_f32_16x16x32_bf16(ahi, bl1, acc1, 0, 0, 0);
        acc1 = __builtin_amdgcn_mfma_f32_16x16x32_bf16(alo, bh1, acc1, 0, 0, 0);
    }
    int rowb = rg * 16 + (lane >> 4) * 4;
    int col0 = colb + ar;
    float bias0 = bout[col0], bias1 = bout[col0 + 16];
    #pragma unroll
    for (int q = 0; q < 4; ++q) {
        out[(rowb + q) * 512 + col0]      = acc0[q] + bias0;
        out[(rowb + q) * 512 + col0 + 16] = acc1[q] + bias1;
    }
}

extern "C" void kernel_launch(void* const* d_in, const int* in_sizes, int n_in,
                              void* d_out, int out_size, void* d_ws, size_t ws_size,
                              hipStream_t stream) {
    const float* x     = (const float*)d_in[0];
    const float* Wqkv  = (const float*)d_in[1];
    const float* theta = (const float*)d_in[2];
    const float* Wout  = (const float*)d_in[3];
    const float* bout  = (const float*)d_in[4];

    float* out  = (float*)d_out;                  // [2,1024,512]
    float* attn = out + 2 * 1024 * 512;           // [2,8,1024,1024]

    float* ws  = (float*)d_ws;
    float* Wqp = ws;                               // 32768
    float* Wkp = ws + 32768;                       // 32768
    float* qp  = ws + 65536;                       // 131072
    float* kp  = ws + 196608;                      // 131072
    unsigned short* vThi = (unsigned short*)(ws + 327680);   // 1,048,576 u16
    unsigned short* vTlo = (unsigned short*)(ws + 851968);   // 1,048,576 u16
    float* oh   = ws + 1376256;                    // 1048576
    // xhi/xlo alias oh: read by k_proj, dead before k_attn_pv writes oh
    unsigned short* xhi = (unsigned short*)(ws + 1376256);   // 1,048,576 u16
    unsigned short* xlo = (unsigned short*)(ws + 1900544);   // 1,048,576 u16
    float* Wv   = ws + 2424832;                    // 262144
    unsigned short* WoThi = (unsigned short*)(ws + 2686976); // 262144 u16
    unsigned short* WoTlo = (unsigned short*)(ws + 2818048); // 262144 u16
    unsigned short* WThi  = (unsigned short*)(ws + 2949120); // 327,680 u16
    unsigned short* WTlo  = (unsigned short*)(ws + 3112960); // 327,680 u16

    k_wproj   <<<128,  256, 0, stream>>>(Wqkv, theta, Wout, x, Wqp, Wkp, Wv, WoThi, WoTlo, xhi, xlo);
    k_wsplit  <<<80,   256, 0, stream>>>(Wqp, Wkp, Wv, WThi, WTlo);
    k_proj    <<<640,  256, 0, stream>>>(xhi, xlo, WThi, WTlo, qp, kp, vThi, vTlo);
    k_attn_pv <<<2048, 512, 0, stream>>>(qp, kp, vThi, vTlo, attn, oh);
    k_out     <<<512,  256, 0, stream>>>(oh, WoThi, WoTlo, bout, out);
}

// Round 21
// 130.496 us; speedup vs baseline: 1.0676x; 1.0092x over previous
//
#include <hip/hip_runtime.h>
#include <hip/hip_bf16.h>

// Sizes (fixed): b=2, n=1024, dim=512, h=8, L=8, dh=64
// exp(-d2/T) with T=0.1 -> exp2(C*d2), C = -10*log2(e)
#define CEXP (-14.4269504088896340736f)

typedef __attribute__((ext_vector_type(8))) short bfrag8;   // 8 bf16 (4 VGPR) MFMA operand
typedef __attribute__((ext_vector_type(4))) float fvec4;    // MFMA accumulator / 16B vec
typedef __attribute__((ext_vector_type(8))) unsigned short ushort8;
typedef __attribute__((ext_vector_type(4))) unsigned short ushort4v;

__device__ inline unsigned short f2bf(float f) {            // RNE float->bf16
    unsigned u = __builtin_bit_cast(unsigned, f);
    u += 0x7fffu + ((u >> 16) & 1u);
    return (unsigned short)(u >> 16);
}
__device__ inline float bf2f(unsigned short h) {
    unsigned u = ((unsigned)h) << 16;
    return __builtin_bit_cast(float, u);
}

// Wave64 sum via DPP (rocPRIM pattern). ctrl/rmask immediates via template params.
template <int CTRL, int RMASK>
__device__ __forceinline__ float dpp_add(float v) {
    int m = __builtin_amdgcn_update_dpp(0, __builtin_bit_cast(int, v), CTRL, RMASK, 0xf, true);
    return v + __builtin_bit_cast(float, m);
}
__device__ __forceinline__ float wave_sum64(float v) {
    v = dpp_add<0xB1,  0xf>(v);   // quad_perm(1,0,3,2)
    v = dpp_add<0x4E,  0xf>(v);   // quad_perm(2,3,0,1)
    v = dpp_add<0x141, 0xf>(v);   // row_half_mirror
    v = dpp_add<0x140, 0xf>(v);   // row_mirror
    v = dpp_add<0x142, 0xa>(v);   // row_bcast15 into rows 1,3
    v = dpp_add<0x143, 0xc>(v);   // row_bcast31 into rows 2,3
    return __builtin_bit_cast(float, __builtin_amdgcn_readlane(__builtin_bit_cast(int, v), 63));
}

// ---------------- K_B: all weight prep + x hi/lo split, single kernel -----------------
// 128 blocks. Per block (c0b = blk*4): Wqp/Wkp panels -> WT rows 0-127 (transposed,
// bf16 hi/lo); Wv panel -> WT rows 128-639; x-split 8192 floats; blocks<64: WoutT.
__global__ __launch_bounds__(256) void k_wproj(const float* __restrict__ Wqkv,
                                               const float* __restrict__ theta,
                                               const float* __restrict__ Wout,
                                               const float* __restrict__ x,
                                               unsigned short* __restrict__ WThi,
                                               unsigned short* __restrict__ WTlo,
                                               unsigned short* __restrict__ WoThi,
                                               unsigned short* __restrict__ WoTlo,
                                               unsigned short* __restrict__ xhi,
                                               unsigned short* __restrict__ xlo) {
    __shared__ float th_s[64 * 65];
    __shared__ float ts2[64 * 65];
    __shared__ float tq[4][64];
    __shared__ float tk[4][64];
    __shared__ float wvs[4][512];
    int tid = threadIdx.x;
    int hl = tid & 63, cl = tid >> 6;
    #pragma unroll
    for (int i = 0; i < 16; ++i) {
        int r = cl * 16 + i;
        th_s[r * 65 + hl] = theta[r * 64 + hl];
    }
    __syncthreads();
    const float* ts = th_s + hl * 65;
    float ss = 0.f;
    #pragma unroll 8
    for (int d = 0; d < 64; ++d) ss = fmaf(ts[d], ts[d], ss);
    float inv = rsqrtf(ss);
    int c0b = blockIdx.x * 4;
    int c = c0b + cl;
    int h = hl >> 3;
    const float* wq = Wqkv + c * 1536 + h * 64;
    const float* wk = wq + 512;
    float aq = 0.f, ak = 0.f;
    #pragma unroll 4
    for (int d = 0; d < 64; ++d) {
        float tv = ts[d];
        aq = fmaf(wq[d], tv, aq);
        ak = fmaf(wk[d], tv, ak);
    }
    tq[cl][hl] = aq * inv;
    tk[cl][hl] = ak * inv;

    // stage Wv panel (4 rows x 512) into LDS
    {
        const float4* src = (const float4*)(Wqkv + 1024);
        #pragma unroll
        for (int j = 0; j < 2; ++j) {
            int idx = j * 256 + tid;
            int rloc = idx >> 7, o4 = idx & 127;
            float4 v = src[(c0b + rloc) * 384 + o4];
            *(float4*)(&wvs[rloc][o4 * 4]) = v;
        }
    }

    // x split: 128 blocks x 8192 floats -> xhi/xlo bf16
    {
        const float4* x4 = (const float4*)x;
        int base4 = blockIdx.x * 2048;
        #pragma unroll
        for (int j = 0; j < 8; ++j) {
            int idx = base4 + j * 256 + tid;
            float4 v = x4[idx];
            float vv[4] = {v.x, v.y, v.z, v.w};
            ushort4v h4, l4;
            #pragma unroll
            for (int jj = 0; jj < 4; ++jj) {
                unsigned short hi = f2bf(vv[jj]);
                h4[jj] = hi;
                l4[jj] = f2bf(vv[jj] - bf2f(hi));
            }
            *(ushort4v*)(xhi + (size_t)idx * 4) = h4;
            *(ushort4v*)(xlo + (size_t)idx * 4) = l4;
        }
    }
    __syncthreads();

    // transposed q/k write: WT[n][k] rows 0-63 (q), 64-127 (k); k = c0b..c0b+3
    {
        int n = tid & 63, g = tid >> 6;      // g: 0 q-hi, 1 q-lo, 2 k-hi, 3 k-lo
        const float (*tp)[64] = (g < 2) ? tq : tk;
        float vsrc[4];
        #pragma unroll
        for (int j = 0; j < 4; ++j) vsrc[j] = tp[j][n];
        ushort4v st;
        if ((g & 1) == 0) {
            #pragma unroll
            for (int j = 0; j < 4; ++j) st[j] = f2bf(vsrc[j]);
        } else {
            #pragma unroll
            for (int j = 0; j < 4; ++j) {
                unsigned short hi = f2bf(vsrc[j]);
                st[j] = f2bf(vsrc[j] - bf2f(hi));
            }
        }
        unsigned short* base = ((g & 1) == 0) ? WThi : WTlo;
        int nrow = (g < 2) ? n : (64 + n);
        *(ushort4v*)(base + (size_t)nrow * 512 + c0b) = st;
    }
    // transposed Wv write: WT rows 128..639
    #pragma unroll
    for (int j2 = 0; j2 < 2; ++j2) {
        int n = j2 * 256 + tid;
        ushort4v h4, l4;
        #pragma unroll
        for (int k = 0; k < 4; ++k) {
            float v = wvs[k][n];
            unsigned short hi = f2bf(v);
            h4[k] = hi;
            l4[k] = f2bf(v - bf2f(hi));
        }
        *(ushort4v*)(WThi + (size_t)(128 + n) * 512 + c0b) = h4;
        *(ushort4v*)(WTlo + (size_t)(128 + n) * 512 + c0b) = l4;
    }

    // blocks 0..63: WoutT[n][c] = Wout[c][n] as bf16 hi/lo (64x64 tiles, LDS transpose)
    if (blockIdx.x < 64) {
        int r0 = (blockIdx.x >> 3) * 64;
        int c0 = (blockIdx.x & 7) * 64;
        int cc = tid & 63, rr = tid >> 6;
        #pragma unroll
        for (int k = 0; k < 16; ++k) {
            int r = rr + 4 * k;
            ts2[r * 65 + cc] = Wout[(r0 + r) * 512 + c0 + cc];
        }
        __syncthreads();
        int kk = tid & 63, nn = tid >> 6;
        #pragma unroll
        for (int i = 0; i < 16; ++i) {
            int n = nn + 4 * i;
            float v = ts2[kk * 65 + n];
            unsigned short hi = f2bf(v);
            WoThi[(size_t)(c0 + n) * 512 + r0 + kk] = hi;
            WoTlo[(size_t)(c0 + n) * 512 + r0 + kk] = f2bf(v - bf2f(hi));
        }
    }
}

// ---------------- K_P: mega projection GEMM via MFMA: [qp|kp|vT] = x @ WallT^T --------
// 640 blocks = 128 rowgroups(16 rows) x 5 col-slices(128); 256 thr / 4 waves;
// wave = 32 cols (2 tiles); A = xhi/xlo staged in swizzled LDS; 3-term hi/lo MFMA.
__global__ __launch_bounds__(256) void k_proj(const unsigned short* __restrict__ xhi,
                                              const unsigned short* __restrict__ xlo,
                                              const unsigned short* __restrict__ WThi,
                                              const unsigned short* __restrict__ WTlo,
                                              float* __restrict__ qp,
                                              float* __restrict__ kp,
                                              unsigned short* __restrict__ vThi,
                                              unsigned short* __restrict__ vTlo) {
    __shared__ unsigned short ps[32 * 512];  // rows 0-15 hi, 16-31 lo; 32 KB
    int blk = blockIdx.x;                    // 640
    int cs = blk % 5;
    int rg = blk / 5;                        // 128 rowgroups
    int tid = threadIdx.x;
    int w = tid >> 6, lane = tid & 63;

    const ushort8* xh8 = (const ushort8*)(xhi + (size_t)rg * 16 * 512);
    const ushort8* xl8 = (const ushort8*)(xlo + (size_t)rg * 16 * 512);
    #pragma unroll
    for (int rep = 0; rep < 4; ++rep) {
        int idx = rep * 256 + tid;           // 1024 = 16 rows x 64 chunks
        int row = idx >> 6, c8 = (idx & 63) * 8;
        int swz = (row & 7) << 3;
        *(ushort8*)(ps + row * 512 + (c8 ^ swz))        = xh8[idx];
        *(ushort8*)(ps + (row + 16) * 512 + (c8 ^ swz)) = xl8[idx];
    }
    __syncthreads();

    int ar  = lane & 15;
    int asw = (ar & 7) << 3;
    int ak  = (lane >> 4) * 8;
    const unsigned short* aph = ps + ar * 512;
    const unsigned short* apl = ps + (ar + 16) * 512;
    int colb = cs * 128 + w * 32;
    size_t b0 = (size_t)(colb + ar) * 512 + ak;
    size_t b1 = b0 + 16 * 512;
    fvec4 acc0 = {0.f, 0.f, 0.f, 0.f};
    fvec4 acc1 = {0.f, 0.f, 0.f, 0.f};
    #pragma unroll 4
    for (int s = 0; s < 16; ++s) {
        int ko = s * 32 + ak;
        bfrag8 ahi = *(const bfrag8*)(aph + (ko ^ asw));
        bfrag8 alo = *(const bfrag8*)(apl + (ko ^ asw));
        bfrag8 bh0 = *(const bfrag8*)(WThi + b0 + s * 32);
        bfrag8 bl0 = *(const bfrag8*)(WTlo + b0 + s * 32);
        bfrag8 bh1 = *(const bfrag8*)(WThi + b1 + s * 32);
        bfrag8 bl1 = *(const bfrag8*)(WTlo + b1 + s * 32);
        acc0 = __builtin_amdgcn_mfma_f32_16x16x32_bf16(ahi, bh0, acc0, 0, 0, 0);
        acc0 = __builtin_amdgcn_mfma_f32_16x16x32_bf16(ahi, bl0, acc0, 0, 0, 0);
        acc0 = __builtin_amdgcn_mfma_f32_16x16x32_bf16(alo, bh0, acc0, 0, 0, 0);
        acc1 = __builtin_amdgcn_mfma_f32_16x16x32_bf16(ahi, bh1, acc1, 0, 0, 0);
        acc1 = __builtin_amdgcn_mfma_f32_16x16x32_bf16(ahi, bl1, acc1, 0, 0, 0);
        acc1 = __builtin_amdgcn_mfma_f32_16x16x32_bf16(alo, bh1, acc1, 0, 0, 0);
    }

    int rowb = rg * 16 + (lane >> 4) * 4;
    int b = rowb >> 10, n = rowb & 1023;
    fvec4 accs[2] = {acc0, acc1};
    #pragma unroll
    for (int t = 0; t < 2; ++t) {
        int col = colb + t * 16 + ar;
        fvec4 a = accs[t];
        if (col < 128) {
            int hl = col & 63;
            float* dstp = (col < 64) ? qp : kp;
            fvec4 st;
            st[0] = a[0] * 0.125f; st[1] = a[1] * 0.125f;
            st[2] = a[2] * 0.125f; st[3] = a[3] * 0.125f;
            *(fvec4*)(dstp + ((size_t)((b * 8 + (hl >> 3)) * 8 + (hl & 7))) * 1024 + n) = st;
        } else {
            int vcol = col - 128;
            int h = vcol >> 6, d = vcol & 63;
            ushort4v h4, l4;
            #pragma unroll
            for (int q = 0; q < 4; ++q) {
                unsigned short hi = f2bf(a[q]);
                h4[q] = hi;
                l4[q] = f2bf(a[q] - bf2f(hi));
            }
            size_t off = (size_t)(b * 8 + h) * 65536 + (size_t)d * 1024 + n;
            *(ushort4v*)(vThi + off) = h4;
            *(ushort4v*)(vTlo + off) = l4;
        }
    }
}

// ---------------- K_E: fused attention rows + MFMA PV; 512 thr / 8 waves --------------
// r17-exact; delta: oh written as bf16 hi/lo pair (feeds k_out staging directly).
__global__ __launch_bounds__(512) void k_attn_pv(const float* __restrict__ qp,
                                                 const float* __restrict__ kp,
                                                 const unsigned short* __restrict__ vThi,
                                                 const unsigned short* __restrict__ vTlo,
                                                 float* __restrict__ attn,
                                                 unsigned short* __restrict__ ohhi,
                                                 unsigned short* __restrict__ ohlo) {
    __shared__ float s_buf[8 * 1024];        // kp (f32) phase 1; P hi/lo bf16 [16][1024] phase 2
    __shared__ float sc[4 * 64 * 4];         // 4 KB split-K combine scratch
    int bx = blockIdx.x;                     // 2048
    int idx = bx >> 3;                       // [0,256)
    int bh = (bx & 7) * 2 + (idx >> 7);      // XCD-aware: 2 bh per XCD -> L2-resident vT
    int rowbase = (idx & 127) * 8;
    int tid = threadIdx.x;
    int w = tid >> 6, lane = tid & 63;

    const float4* kp4 = (const float4*)(kp + bh * 8192);
    float4* kps4 = (float4*)s_buf;
    #pragma unroll
    for (int k = 0; k < 4; ++k) kps4[k * 512 + tid] = kp4[k * 512 + tid];

    int r = rowbase + w;
    float qv[8];
    #pragma unroll
    for (int l = 0; l < 8; ++l) qv[l] = qp[bh * 8192 + l * 1024 + r];
    __syncthreads();

    const fvec4 CE4 = {CEXP, CEXP, CEXP, CEXP};
    fvec4 acc4[4];
    #pragma unroll
    for (int mm = 0; mm < 4; ++mm) acc4[mm] = (fvec4){0.f, 0.f, 0.f, 0.f};

    for (int l = 0; l < 8; ++l) {
        fvec4 kv4[4], e4[4];
        #pragma unroll
        for (int mm = 0; mm < 4; ++mm)
            kv4[mm] = *(const fvec4*)(s_buf + l * 1024 + mm * 256 + lane * 4);
        float sqs = -2.f * CEXP * qv[l];
        fvec4 sq4 = {sqs, sqs, sqs, sqs};
        fvec4 sum4 = {0.f, 0.f, 0.f, 0.f};
        #pragma unroll
        for (int mm = 0; mm < 4; ++mm) {
            fvec4 k2 = (kv4[mm] * kv4[mm]) * CE4;
            fvec4 t  = sq4 * kv4[mm] + k2;
            fvec4 e;
            e[0] = __builtin_amdgcn_exp2f(t[0]);
            e[1] = __builtin_amdgcn_exp2f(t[1]);
            e[2] = __builtin_amdgcn_exp2f(t[2]);
            e[3] = __builtin_amdgcn_exp2f(t[3]);
            e4[mm] = e;
            sum4 += e;
        }
        float s = (sum4[0] + sum4[1]) + (sum4[2] + sum4[3]);
        float inv = 0.125f * __builtin_amdgcn_rcpf(wave_sum64(s));
        fvec4 inv4 = {inv, inv, inv, inv};
        #pragma unroll
        for (int mm = 0; mm < 4; ++mm) acc4[mm] = e4[mm] * inv4 + acc4[mm];
    }

    __syncthreads();   // all waves done reading kp from s_buf

    unsigned short* ps = (unsigned short*)s_buf;
    int swz = w << 3;
    #pragma unroll
    for (int mm = 0; mm < 4; ++mm) {
        ushort4v h4, l4;
        #pragma unroll
        for (int jj = 0; jj < 4; ++jj) {
            float v = acc4[mm][jj];
            unsigned short hi = f2bf(v);
            h4[jj] = hi;
            l4[jj] = f2bf(v - bf2f(hi));
        }
        int j0 = mm * 256 + lane * 4;
        *(ushort4v*)(ps + w * 1024 + (j0 ^ swz))       = h4;
        *(ushort4v*)(ps + (w + 8) * 1024 + (j0 ^ swz)) = l4;
    }
    __syncthreads();

    float* aR = attn + ((size_t)(bh * 1024 + r)) * 1024;
    #pragma unroll
    for (int mm = 0; mm < 4; ++mm)
        __builtin_nontemporal_store(acc4[mm], (fvec4*)(aR + mm * 256 + lane * 4));

    // Phase 2: wave w -> cols n0..n0+15, K-half kh; pairs (w, w+4) combine via LDS.
    int n0 = (w & 3) * 16;
    int kh = w >> 2;
    int ar  = lane & 15;
    int asw = (ar & 7) << 3;
    int ak  = (lane >> 4) * 8;
    const unsigned short* ap = ps + ar * 1024;
    size_t boff = (size_t)bh * 65536 + (size_t)(n0 + ar) * 1024 + ak;
    const unsigned short* bh_p = vThi + boff;
    const unsigned short* bl_p = vTlo + boff;
    fvec4 c2 = {0.f, 0.f, 0.f, 0.f};
    #pragma unroll 4
    for (int s = kh * 16; s < kh * 16 + 16; ++s) {
        bfrag8 a  = *(const bfrag8*)(ap + ((s * 32 + ak) ^ asw));
        bfrag8 vh = *(const bfrag8*)(bh_p + s * 32);
        bfrag8 vl = *(const bfrag8*)(bl_p + s * 32);
        c2 = __builtin_amdgcn_mfma_f32_16x16x32_bf16(a, vh, c2, 0, 0, 0);
        c2 = __builtin_amdgcn_mfma_f32_16x16x32_bf16(a, vl, c2, 0, 0, 0);
    }
    if (w >= 4) {
        #pragma unroll
        for (int q = 0; q < 4; ++q) sc[(w - 4) * 256 + lane * 4 + q] = c2[q];
    }
    __syncthreads();
    if (w < 4) {
        int b = bh >> 3, h = bh & 7;
        #pragma unroll
        for (int q = 0; q < 4; ++q) {
            float t = c2[q] + sc[w * 256 + lane * 4 + q];
            t += __shfl_xor(t, 32);               // hi row + lo row
            if (lane < 32) {
                int row = rowbase + (lane >> 4) * 4 + q;
                size_t o = (size_t)(b * 1024 + row) * 512 + h * 64 + n0 + ar;
                unsigned short hi = f2bf(t);
                ohhi[o] = hi;
                ohlo[o] = f2bf(t - bf2f(hi));
            }
        }
    }
}

// ---------------- K_G: out = oh @ W_out + b_out via MFMA (bf16 hi/lo, 3-term) ---------
// oh arrives pre-split (ohhi/ohlo) -> staging is plain ushort8 copies.
__global__ __launch_bounds__(256) void k_out(const unsigned short* __restrict__ ohhi,
                                             const unsigned short* __restrict__ ohlo,
                                             const unsigned short* __restrict__ WoThi,
                                             const unsigned short* __restrict__ WoTlo,
                                             const float* __restrict__ bout,
                                             float* __restrict__ out) {
    __shared__ unsigned short ps[32 * 512];  // rows 0-15 hi, 16-31 lo; 32 KB
    int blk = blockIdx.x;                    // 512
    int cs = blk & 3;
    int rg = blk >> 2;                       // 128 row-groups
    int tid = threadIdx.x;
    int w = tid >> 6, lane = tid & 63;

    const ushort8* ogh = (const ushort8*)(ohhi + (size_t)rg * 16 * 512);
    const ushort8* ogl = (const ushort8*)(ohlo + (size_t)rg * 16 * 512);
    #pragma unroll
    for (int rep = 0; rep < 4; ++rep) {
        int idx = rep * 256 + tid;           // 1024 = 16 rows x 64 chunks
        int row = idx >> 6, c8 = (idx & 63) * 8;
        int swz = (row & 7) << 3;
        *(ushort8*)(ps + row * 512 + (c8 ^ swz))        = ogh[idx];
        *(ushort8*)(ps + (row + 16) * 512 + (c8 ^ swz)) = ogl[idx];
    }
    __syncthreads();

    int ar  = lane & 15;
    int asw = (ar & 7) << 3;
    int ak  = (lane >> 4) * 8;
    const unsigned short* aph = ps + ar * 512;
    const unsigned short* apl = ps + (ar + 16) * 512;
    int colb = cs * 128 + w * 32;
    size_t b0 = (size_t)(colb + ar) * 512 + ak;
    size_t b1 = b0 + 16 * 512;
    fvec4 acc0 = {0.f, 0.f, 0.f, 0.f};
    fvec4 acc1 = {0.f, 0.f, 0.f, 0.f};
    #pragma unroll 4
    for (int s = 0; s < 16; ++s) {
        int ko = s * 32 + ak;
        bfrag8 ahi = *(const bfrag8*)(aph + (ko ^ asw));
        bfrag8 alo = *(const bfrag8*)(apl + (ko ^ asw));
        bfrag8 bh0 = *(const bfrag8*)(WoThi + b0 + s * 32);
        bfrag8 bl0 = *(const bfrag8*)(WoTlo + b0 + s * 32);
        bfrag8 bh1 = *(const bfrag8*)(WoThi + b1 + s * 32);
        bfrag8 bl1 = *(const bfrag8*)(WoTlo + b1 + s * 32);
        acc0 = __builtin_amdgcn_mfma_f32_16x16x32_bf16(ahi, bh0, acc0, 0, 0, 0);
        acc0 = __builtin_amdgcn_mfma_f32_16x16x32_bf16(ahi, bl0, acc0, 0, 0, 0);
        acc0 = __builtin_amdgcn_mfma_f32_16x16x32_bf16(alo, bh0, acc0, 0, 0, 0);
        acc1 = __builtin_amdgcn_mfma_f32_16x16x32_bf16(ahi, bh1, acc1, 0, 0, 0);
        acc1 = __builtin_amdgcn_mfma_f32_16x16x32_bf16(ahi, bl1, acc1, 0, 0, 0);
        acc1 = __builtin_amdgcn_mfma_f32_16x16x32_bf16(alo, bh1, acc1, 0, 0, 0);
    }
    int rowb = rg * 16 + (lane >> 4) * 4;
    int col0 = colb + ar;
    float bias0 = bout[col0], bias1 = bout[col0 + 16];
    #pragma unroll
    for (int q = 0; q < 4; ++q) {
        out[(rowb + q) * 512 + col0]      = acc0[q] + bias0;
        out[(rowb + q) * 512 + col0 + 16] = acc1[q] + bias1;
    }
}

extern "C" void kernel_launch(void* const* d_in, const int* in_sizes, int n_in,
                              void* d_out, int out_size, void* d_ws, size_t ws_size,
                              hipStream_t stream) {
    const float* x     = (const float*)d_in[0];
    const float* Wqkv  = (const float*)d_in[1];
    const float* theta = (const float*)d_in[2];
    const float* Wout  = (const float*)d_in[3];
    const float* bout  = (const float*)d_in[4];

    float* out  = (float*)d_out;                  // [2,1024,512]
    float* attn = out + 2 * 1024 * 512;           // [2,8,1024,1024]

    float* ws  = (float*)d_ws;
    float* qp  = ws + 65536;                       // 131072
    float* kp  = ws + 196608;                      // 131072
    unsigned short* vThi = (unsigned short*)(ws + 327680);   // 1,048,576 u16
    unsigned short* vTlo = (unsigned short*)(ws + 851968);   // 1,048,576 u16
    // xhi/xlo (k_proj input) share slots with ohhi/ohlo (attn output): xs dead after k_proj
    unsigned short* xhi = (unsigned short*)(ws + 1376256);   // 1,048,576 u16
    unsigned short* xlo = (unsigned short*)(ws + 1900544);   // 1,048,576 u16
    unsigned short* ohhi = xhi;
    unsigned short* ohlo = xlo;
    unsigned short* WoThi = (unsigned short*)(ws + 2686976); // 262144 u16
    unsigned short* WoTlo = (unsigned short*)(ws + 2818048); // 262144 u16
    unsigned short* WThi  = (unsigned short*)(ws + 2949120); // 327,680 u16
    unsigned short* WTlo  = (unsigned short*)(ws + 3112960); // 327,680 u16

    k_wproj   <<<128,  256, 0, stream>>>(Wqkv, theta, Wout, x, WThi, WTlo, WoThi, WoTlo, xhi, xlo);
    k_proj    <<<640,  256, 0, stream>>>(xhi, xlo, WThi, WTlo, qp, kp, vThi, vTlo);
    k_attn_pv <<<2048, 512, 0, stream>>>(qp, kp, vThi, vTlo, attn, ohhi, ohlo);
    k_out     <<<512,  256, 0, stream>>>(ohhi, ohlo, WoThi, WoTlo, bout, out);
}

// Round 22
// 126.492 us; speedup vs baseline: 1.1014x; 1.0317x over previous
//
#include <hip/hip_runtime.h>
#include <hip/hip_bf16.h>

// Sizes (fixed): b=2, n=1024, dim=512, h=8, L=8, dh=64
// exp(-d2/T) with T=0.1 -> exp2(C*d2), C = -10*log2(e)
#define CEXP (-14.4269504088896340736f)

typedef __attribute__((ext_vector_type(8))) short bfrag8;   // 8 bf16 (4 VGPR) MFMA operand
typedef __attribute__((ext_vector_type(4))) float fvec4;    // MFMA accumulator / 16B vec
typedef __attribute__((ext_vector_type(8))) unsigned short ushort8;
typedef __attribute__((ext_vector_type(4))) unsigned short ushort4v;

__device__ inline unsigned short f2bf(float f) {            // RNE float->bf16
    unsigned u = __builtin_bit_cast(unsigned, f);
    u += 0x7fffu + ((u >> 16) & 1u);
    return (unsigned short)(u >> 16);
}
__device__ inline float bf2f(unsigned short h) {
    unsigned u = ((unsigned)h) << 16;
    return __builtin_bit_cast(float, u);
}

// Wave64 sum via DPP (rocPRIM pattern). ctrl/rmask immediates via template params.
template <int CTRL, int RMASK>
__device__ __forceinline__ float dpp_add(float v) {
    int m = __builtin_amdgcn_update_dpp(0, __builtin_bit_cast(int, v), CTRL, RMASK, 0xf, true);
    return v + __builtin_bit_cast(float, m);
}
__device__ __forceinline__ float wave_sum64(float v) {
    v = dpp_add<0xB1,  0xf>(v);   // quad_perm(1,0,3,2)
    v = dpp_add<0x4E,  0xf>(v);   // quad_perm(2,3,0,1)
    v = dpp_add<0x141, 0xf>(v);   // row_half_mirror
    v = dpp_add<0x140, 0xf>(v);   // row_mirror
    v = dpp_add<0x142, 0xa>(v);   // row_bcast15 into rows 1,3
    v = dpp_add<0x143, 0xc>(v);   // row_bcast31 into rows 2,3
    return __builtin_bit_cast(float, __builtin_amdgcn_readlane(__builtin_bit_cast(int, v), 63));
}

// ---------------- K_B: all weight prep, single kernel ---------------------------------
// 128 blocks. Per block (c0b = blk*4): Wqp/Wkp panels -> WT rows 0-127 (transposed,
// bf16 hi/lo); Wv panel -> WT rows 128-639; blocks<64: WoutT.
__global__ __launch_bounds__(256) void k_wproj(const float* __restrict__ Wqkv,
                                               const float* __restrict__ theta,
                                               const float* __restrict__ Wout,
                                               unsigned short* __restrict__ WThi,
                                               unsigned short* __restrict__ WTlo,
                                               unsigned short* __restrict__ WoThi,
                                               unsigned short* __restrict__ WoTlo) {
    __shared__ float th_s[64 * 65];
    __shared__ float ts2[64 * 65];
    __shared__ float tq[4][64];
    __shared__ float tk[4][64];
    __shared__ float wvs[4][512];
    int tid = threadIdx.x;
    int hl = tid & 63, cl = tid >> 6;
    #pragma unroll
    for (int i = 0; i < 16; ++i) {
        int r = cl * 16 + i;
        th_s[r * 65 + hl] = theta[r * 64 + hl];
    }
    __syncthreads();
    const float* ts = th_s + hl * 65;
    float ss = 0.f;
    #pragma unroll 8
    for (int d = 0; d < 64; ++d) ss = fmaf(ts[d], ts[d], ss);
    float inv = rsqrtf(ss);
    int c0b = blockIdx.x * 4;
    int c = c0b + cl;
    int h = hl >> 3;
    const float* wq = Wqkv + c * 1536 + h * 64;
    const float* wk = wq + 512;
    float aq = 0.f, ak = 0.f;
    #pragma unroll 4
    for (int d = 0; d < 64; ++d) {
        float tv = ts[d];
        aq = fmaf(wq[d], tv, aq);
        ak = fmaf(wk[d], tv, ak);
    }
    tq[cl][hl] = aq * inv;
    tk[cl][hl] = ak * inv;

    // stage Wv panel (4 rows x 512) into LDS
    {
        const float4* src = (const float4*)(Wqkv + 1024);
        #pragma unroll
        for (int j = 0; j < 2; ++j) {
            int idx = j * 256 + tid;
            int rloc = idx >> 7, o4 = idx & 127;
            float4 v = src[(c0b + rloc) * 384 + o4];
            *(float4*)(&wvs[rloc][o4 * 4]) = v;
        }
    }
    __syncthreads();

    // transposed q/k write: WT[n][k] rows 0-63 (q), 64-127 (k); k = c0b..c0b+3
    {
        int n = tid & 63, g = tid >> 6;      // g: 0 q-hi, 1 q-lo, 2 k-hi, 3 k-lo
        const float (*tp)[64] = (g < 2) ? tq : tk;
        float vsrc[4];
        #pragma unroll
        for (int j = 0; j < 4; ++j) vsrc[j] = tp[j][n];
        ushort4v st;
        if ((g & 1) == 0) {
            #pragma unroll
            for (int j = 0; j < 4; ++j) st[j] = f2bf(vsrc[j]);
        } else {
            #pragma unroll
            for (int j = 0; j < 4; ++j) {
                unsigned short hi = f2bf(vsrc[j]);
                st[j] = f2bf(vsrc[j] - bf2f(hi));
            }
        }
        unsigned short* base = ((g & 1) == 0) ? WThi : WTlo;
        int nrow = (g < 2) ? n : (64 + n);
        *(ushort4v*)(base + (size_t)nrow * 512 + c0b) = st;
    }
    // transposed Wv write: WT rows 128..639
    #pragma unroll
    for (int j2 = 0; j2 < 2; ++j2) {
        int n = j2 * 256 + tid;
        ushort4v h4, l4;
        #pragma unroll
        for (int k = 0; k < 4; ++k) {
            float v = wvs[k][n];
            unsigned short hi = f2bf(v);
            h4[k] = hi;
            l4[k] = f2bf(v - bf2f(hi));
        }
        *(ushort4v*)(WThi + (size_t)(128 + n) * 512 + c0b) = h4;
        *(ushort4v*)(WTlo + (size_t)(128 + n) * 512 + c0b) = l4;
    }

    // blocks 0..63: WoutT[n][c] = Wout[c][n] as bf16 hi/lo (64x64 tiles, LDS transpose)
    if (blockIdx.x < 64) {
        int r0 = (blockIdx.x >> 3) * 64;
        int c0 = (blockIdx.x & 7) * 64;
        int cc = tid & 63, rr = tid >> 6;
        #pragma unroll
        for (int k = 0; k < 16; ++k) {
            int r = rr + 4 * k;
            ts2[r * 65 + cc] = Wout[(r0 + r) * 512 + c0 + cc];
        }
        __syncthreads();
        int kk = tid & 63, nn = tid >> 6;
        #pragma unroll
        for (int i = 0; i < 16; ++i) {
            int n = nn + 4 * i;
            float v = ts2[kk * 65 + n];
            unsigned short hi = f2bf(v);
            WoThi[(size_t)(c0 + n) * 512 + r0 + kk] = hi;
            WoTlo[(size_t)(c0 + n) * 512 + r0 + kk] = f2bf(v - bf2f(hi));
        }
    }
}

// ---------------- K_P: mega projection GEMM via MFMA: [qp|kp|vT] = x @ WallT^T --------
// 640 blocks = 128 rowgroups(16 rows) x 5 col-slices(128); 256 thr / 4 waves;
// wave = 32 cols (2 tiles); A = x (f32) hi/lo-split during LDS staging; 3-term MFMA.
__global__ __launch_bounds__(256) void k_proj(const float* __restrict__ x,
                                              const unsigned short* __restrict__ WThi,
                                              const unsigned short* __restrict__ WTlo,
                                              float* __restrict__ qp,
                                              float* __restrict__ kp,
                                              unsigned short* __restrict__ vThi,
                                              unsigned short* __restrict__ vTlo) {
    __shared__ unsigned short ps[32 * 512];  // rows 0-15 hi, 16-31 lo; 32 KB
    int blk = blockIdx.x;                    // 640
    int cs = blk % 5;
    int rg = blk / 5;                        // 128 rowgroups
    int tid = threadIdx.x;
    int w = tid >> 6, lane = tid & 63;

    const float4* xg = (const float4*)(x + (size_t)rg * 16 * 512);
    #pragma unroll
    for (int rep = 0; rep < 8; ++rep) {
        int idx = rep * 256 + tid;           // 2048 float4 = 16 rows x 128
        int row = idx >> 7, c4 = idx & 127;
        float4 v = xg[idx];
        int swz = (row & 7) << 3;
        int cbase = c4 * 4;
        ushort4v h4, l4;
        float vv[4] = {v.x, v.y, v.z, v.w};
        #pragma unroll
        for (int jj = 0; jj < 4; ++jj) {
            unsigned short hi = f2bf(vv[jj]);
            h4[jj] = hi;
            l4[jj] = f2bf(vv[jj] - bf2f(hi));
        }
        *(ushort4v*)(ps + row * 512 + (cbase ^ swz))        = h4;
        *(ushort4v*)(ps + (row + 16) * 512 + (cbase ^ swz)) = l4;
    }
    __syncthreads();

    int ar  = lane & 15;
    int asw = (ar & 7) << 3;
    int ak  = (lane >> 4) * 8;
    const unsigned short* aph = ps + ar * 512;
    const unsigned short* apl = ps + (ar + 16) * 512;
    int colb = cs * 128 + w * 32;
    size_t b0 = (size_t)(colb + ar) * 512 + ak;
    size_t b1 = b0 + 16 * 512;
    fvec4 acc0 = {0.f, 0.f, 0.f, 0.f};
    fvec4 acc1 = {0.f, 0.f, 0.f, 0.f};
    #pragma unroll 4
    for (int s = 0; s < 16; ++s) {
        int ko = s * 32 + ak;
        bfrag8 ahi = *(const bfrag8*)(aph + (ko ^ asw));
        bfrag8 alo = *(const bfrag8*)(apl + (ko ^ asw));
        bfrag8 bh0 = *(const bfrag8*)(WThi + b0 + s * 32);
        bfrag8 bl0 = *(const bfrag8*)(WTlo + b0 + s * 32);
        bfrag8 bh1 = *(const bfrag8*)(WThi + b1 + s * 32);
        bfrag8 bl1 = *(const bfrag8*)(WTlo + b1 + s * 32);
        acc0 = __builtin_amdgcn_mfma_f32_16x16x32_bf16(ahi, bh0, acc0, 0, 0, 0);
        acc0 = __builtin_amdgcn_mfma_f32_16x16x32_bf16(ahi, bl0, acc0, 0, 0, 0);
        acc0 = __builtin_amdgcn_mfma_f32_16x16x32_bf16(alo, bh0, acc0, 0, 0, 0);
        acc1 = __builtin_amdgcn_mfma_f32_16x16x32_bf16(ahi, bh1, acc1, 0, 0, 0);
        acc1 = __builtin_amdgcn_mfma_f32_16x16x32_bf16(ahi, bl1, acc1, 0, 0, 0);
        acc1 = __builtin_amdgcn_mfma_f32_16x16x32_bf16(alo, bh1, acc1, 0, 0, 0);
    }

    int rowb = rg * 16 + (lane >> 4) * 4;
    int b = rowb >> 10, n = rowb & 1023;
    fvec4 accs[2] = {acc0, acc1};
    #pragma unroll
    for (int t = 0; t < 2; ++t) {
        int col = colb + t * 16 + ar;
        fvec4 a = accs[t];
        if (col < 128) {
            int hl = col & 63;
            float* dstp = (col < 64) ? qp : kp;
            fvec4 st;
            st[0] = a[0] * 0.125f; st[1] = a[1] * 0.125f;
            st[2] = a[2] * 0.125f; st[3] = a[3] * 0.125f;
            *(fvec4*)(dstp + ((size_t)((b * 8 + (hl >> 3)) * 8 + (hl & 7))) * 1024 + n) = st;
        } else {
            int vcol = col - 128;
            int h = vcol >> 6, d = vcol & 63;
            ushort4v h4, l4;
            #pragma unroll
            for (int q = 0; q < 4; ++q) {
                unsigned short hi = f2bf(a[q]);
                h4[q] = hi;
                l4[q] = f2bf(a[q] - bf2f(hi));
            }
            size_t off = (size_t)(b * 8 + h) * 65536 + (size_t)d * 1024 + n;
            *(ushort4v*)(vThi + off) = h4;
            *(ushort4v*)(vTlo + off) = l4;
        }
    }
}

// ---------------- K_E: fused attention rows + MFMA PV; 512 thr / 8 waves --------------
// Frozen structure (r17); oh written as bf16 hi/lo pair.
__global__ __launch_bounds__(512) void k_attn_pv(const float* __restrict__ qp,
                                                 const float* __restrict__ kp,
                                                 const unsigned short* __restrict__ vThi,
                                                 const unsigned short* __restrict__ vTlo,
                                                 float* __restrict__ attn,
                                                 unsigned short* __restrict__ ohhi,
                                                 unsigned short* __restrict__ ohlo) {
    __shared__ float s_buf[8 * 1024];        // kp (f32) phase 1; P hi/lo bf16 [16][1024] phase 2
    __shared__ float sc[4 * 64 * 4];         // 4 KB split-K combine scratch
    int bx = blockIdx.x;                     // 2048
    int idx = bx >> 3;                       // [0,256)
    int bh = (bx & 7) * 2 + (idx >> 7);      // XCD-aware: 2 bh per XCD -> L2-resident vT
    int rowbase = (idx & 127) * 8;
    int tid = threadIdx.x;
    int w = tid >> 6, lane = tid & 63;

    const float4* kp4 = (const float4*)(kp + bh * 8192);
    float4* kps4 = (float4*)s_buf;
    #pragma unroll
    for (int k = 0; k < 4; ++k) kps4[k * 512 + tid] = kp4[k * 512 + tid];

    int r = rowbase + w;
    float qv[8];
    #pragma unroll
    for (int l = 0; l < 8; ++l) qv[l] = qp[bh * 8192 + l * 1024 + r];
    __syncthreads();

    const fvec4 CE4 = {CEXP, CEXP, CEXP, CEXP};
    fvec4 acc4[4];
    #pragma unroll
    for (int mm = 0; mm < 4; ++mm) acc4[mm] = (fvec4){0.f, 0.f, 0.f, 0.f};

    for (int l = 0; l < 8; ++l) {
        fvec4 kv4[4], e4[4];
        #pragma unroll
        for (int mm = 0; mm < 4; ++mm)
            kv4[mm] = *(const fvec4*)(s_buf + l * 1024 + mm * 256 + lane * 4);
        float sqs = -2.f * CEXP * qv[l];
        fvec4 sq4 = {sqs, sqs, sqs, sqs};
        fvec4 sum4 = {0.f, 0.f, 0.f, 0.f};
        #pragma unroll
        for (int mm = 0; mm < 4; ++mm) {
            fvec4 k2 = (kv4[mm] * kv4[mm]) * CE4;
            fvec4 t  = sq4 * kv4[mm] + k2;
            fvec4 e;
            e[0] = __builtin_amdgcn_exp2f(t[0]);
            e[1] = __builtin_amdgcn_exp2f(t[1]);
            e[2] = __builtin_amdgcn_exp2f(t[2]);
            e[3] = __builtin_amdgcn_exp2f(t[3]);
            e4[mm] = e;
            sum4 += e;
        }
        float s = (sum4[0] + sum4[1]) + (sum4[2] + sum4[3]);
        float inv = 0.125f * __builtin_amdgcn_rcpf(wave_sum64(s));
        fvec4 inv4 = {inv, inv, inv, inv};
        #pragma unroll
        for (int mm = 0; mm < 4; ++mm) acc4[mm] = e4[mm] * inv4 + acc4[mm];
    }

    __syncthreads();   // all waves done reading kp from s_buf

    unsigned short* ps = (unsigned short*)s_buf;
    int swz = w << 3;
    #pragma unroll
    for (int mm = 0; mm < 4; ++mm) {
        ushort4v h4, l4;
        #pragma unroll
        for (int jj = 0; jj < 4; ++jj) {
            float v = acc4[mm][jj];
            unsigned short hi = f2bf(v);
            h4[jj] = hi;
            l4[jj] = f2bf(v - bf2f(hi));
        }
        int j0 = mm * 256 + lane * 4;
        *(ushort4v*)(ps + w * 1024 + (j0 ^ swz))       = h4;
        *(ushort4v*)(ps + (w + 8) * 1024 + (j0 ^ swz)) = l4;
    }
    __syncthreads();

    float* aR = attn + ((size_t)(bh * 1024 + r)) * 1024;
    #pragma unroll
    for (int mm = 0; mm < 4; ++mm)
        __builtin_nontemporal_store(acc4[mm], (fvec4*)(aR + mm * 256 + lane * 4));

    // Phase 2: wave w -> cols n0..n0+15, K-half kh; pairs (w, w+4) combine via LDS.
    int n0 = (w & 3) * 16;
    int kh = w >> 2;
    int ar  = lane & 15;
    int asw = (ar & 7) << 3;
    int ak  = (lane >> 4) * 8;
    const unsigned short* ap = ps + ar * 1024;
    size_t boff = (size_t)bh * 65536 + (size_t)(n0 + ar) * 1024 + ak;
    const unsigned short* bh_p = vThi + boff;
    const unsigned short* bl_p = vTlo + boff;
    fvec4 c2 = {0.f, 0.f, 0.f, 0.f};
    #pragma unroll 4
    for (int s = kh * 16; s < kh * 16 + 16; ++s) {
        bfrag8 a  = *(const bfrag8*)(ap + ((s * 32 + ak) ^ asw));
        bfrag8 vh = *(const bfrag8*)(bh_p + s * 32);
        bfrag8 vl = *(const bfrag8*)(bl_p + s * 32);
        c2 = __builtin_amdgcn_mfma_f32_16x16x32_bf16(a, vh, c2, 0, 0, 0);
        c2 = __builtin_amdgcn_mfma_f32_16x16x32_bf16(a, vl, c2, 0, 0, 0);
    }
    if (w >= 4) {
        #pragma unroll
        for (int q = 0; q < 4; ++q) sc[(w - 4) * 256 + lane * 4 + q] = c2[q];
    }
    __syncthreads();
    if (w < 4) {
        int b = bh >> 3, h = bh & 7;
        #pragma unroll
        for (int q = 0; q < 4; ++q) {
            float t = c2[q] + sc[w * 256 + lane * 4 + q];
            t += __shfl_xor(t, 32);               // hi row + lo row
            if (lane < 32) {
                int row = rowbase + (lane >> 4) * 4 + q;
                size_t o = (size_t)(b * 1024 + row) * 512 + h * 64 + n0 + ar;
                unsigned short hi = f2bf(t);
                ohhi[o] = hi;
                ohlo[o] = f2bf(t - bf2f(hi));
            }
        }
    }
}

// ---------------- K_G: out = oh @ W_out + b_out via MFMA (bf16 hi/lo, 3-term) ---------
__global__ __launch_bounds__(256) void k_out(const unsigned short* __restrict__ ohhi,
                                             const unsigned short* __restrict__ ohlo,
                                             const unsigned short* __restrict__ WoThi,
                                             const unsigned short* __restrict__ WoTlo,
                                             const float* __restrict__ bout,
                                             float* __restrict__ out) {
    __shared__ unsigned short ps[32 * 512];  // rows 0-15 hi, 16-31 lo; 32 KB
    int blk = blockIdx.x;                    // 512
    int cs = blk & 3;
    int rg = blk >> 2;                       // 128 row-groups
    int tid = threadIdx.x;
    int w = tid >> 6, lane = tid & 63;

    const ushort8* ogh = (const ushort8*)(ohhi + (size_t)rg * 16 * 512);
    const ushort8* ogl = (const ushort8*)(ohlo + (size_t)rg * 16 * 512);
    #pragma unroll
    for (int rep = 0; rep < 4; ++rep) {
        int idx = rep * 256 + tid;           // 1024 = 16 rows x 64 chunks
        int row = idx >> 6, c8 = (idx & 63) * 8;
        int swz = (row & 7) << 3;
        *(ushort8*)(ps + row * 512 + (c8 ^ swz))        = ogh[idx];
        *(ushort8*)(ps + (row + 16) * 512 + (c8 ^ swz)) = ogl[idx];
    }
    __syncthreads();

    int ar  = lane & 15;
    int asw = (ar & 7) << 3;
    int ak  = (lane >> 4) * 8;
    const unsigned short* aph = ps + ar * 512;
    const unsigned short* apl = ps + (ar + 16) * 512;
    int colb = cs * 128 + w * 32;
    size_t b0 = (size_t)(colb + ar) * 512 + ak;
    size_t b1 = b0 + 16 * 512;
    fvec4 acc0 = {0.f, 0.f, 0.f, 0.f};
    fvec4 acc1 = {0.f, 0.f, 0.f, 0.f};
    #pragma unroll 4
    for (int s = 0; s < 16; ++s) {
        int ko = s * 32 + ak;
        bfrag8 ahi = *(const bfrag8*)(aph + (ko ^ asw));
        bfrag8 alo = *(const bfrag8*)(apl + (ko ^ asw));
        bfrag8 bh0 = *(const bfrag8*)(WoThi + b0 + s * 32);
        bfrag8 bl0 = *(const bfrag8*)(WoTlo + b0 + s * 32);
        bfrag8 bh1 = *(const bfrag8*)(WoThi + b1 + s * 32);
        bfrag8 bl1 = *(const bfrag8*)(WoTlo + b1 + s * 32);
        acc0 = __builtin_amdgcn_mfma_f32_16x16x32_bf16(ahi, bh0, acc0, 0, 0, 0);
        acc0 = __builtin_amdgcn_mfma_f32_16x16x32_bf16(ahi, bl0, acc0, 0, 0, 0);
        acc0 = __builtin_amdgcn_mfma_f32_16x16x32_bf16(alo, bh0, acc0, 0, 0, 0);
        acc1 = __builtin_amdgcn_mfma_f32_16x16x32_bf16(ahi, bh1, acc1, 0, 0, 0);
        acc1 = __builtin_amdgcn_mfma_f32_16x16x32_bf16(ahi, bl1, acc1, 0, 0, 0);
        acc1 = __builtin_amdgcn_mfma_f32_16x16x32_bf16(alo, bh1, acc1, 0, 0, 0);
    }
    int rowb = rg * 16 + (lane >> 4) * 4;
    int col0 = colb + ar;
    float bias0 = bout[col0], bias1 = bout[col0 + 16];
    #pragma unroll
    for (int q = 0; q < 4; ++q) {
        out[(rowb + q) * 512 + col0]      = acc0[q] + bias0;
        out[(rowb + q) * 512 + col0 + 16] = acc1[q] + bias1;
    }
}

extern "C" void kernel_launch(void* const* d_in, const int* in_sizes, int n_in,
                              void* d_out, int out_size, void* d_ws, size_t ws_size,
                              hipStream_t stream) {
    const float* x     = (const float*)d_in[0];
    const float* Wqkv  = (const float*)d_in[1];
    const float* theta = (const float*)d_in[2];
    const float* Wout  = (const float*)d_in[3];
    const float* bout  = (const float*)d_in[4];

    float* out  = (float*)d_out;                  // [2,1024,512]
    float* attn = out + 2 * 1024 * 512;           // [2,8,1024,1024]

    float* ws  = (float*)d_ws;
    float* qp  = ws + 65536;                       // 131072
    float* kp  = ws + 196608;                      // 131072
    unsigned short* vThi = (unsigned short*)(ws + 327680);   // 1,048,576 u16
    unsigned short* vTlo = (unsigned short*)(ws + 851968);   // 1,048,576 u16
    unsigned short* ohhi = (unsigned short*)(ws + 1376256);  // 1,048,576 u16
    unsigned short* ohlo = (unsigned short*)(ws + 1900544);  // 1,048,576 u16
    unsigned short* WoThi = (unsigned short*)(ws + 2686976); // 262144 u16
    unsigned short* WoTlo = (unsigned short*)(ws + 2818048); // 262144 u16
    unsigned short* WThi  = (unsigned short*)(ws + 2949120); // 327,680 u16
    unsigned short* WTlo  = (unsigned short*)(ws + 3112960); // 327,680 u16

    k_wproj   <<<128,  256, 0, stream>>>(Wqkv, theta, Wout, WThi, WTlo, WoThi, WoTlo);
    k_proj    <<<640,  256, 0, stream>>>(x, WThi, WTlo, qp, kp, vThi, vTlo);
    k_attn_pv <<<2048, 512, 0, stream>>>(qp, kp, vThi, vTlo, attn, ohhi, ohlo);
    k_out     <<<512,  256, 0, stream>>>(ohhi, ohlo, WoThi, WoTlo, bout, out);
}